// Round 9
// baseline (1251.198 us; speedup 1.0000x reference)
//
#include <hip/hip_runtime.h>
#include <cstdint>

typedef unsigned long long u64;

#define TPB 256
#define MARGIN 5e-4
#define FCAP (1 << 20)

// ---------------------------------------------------------------------------
// gamma^dist table, fp64 (used by repair_ret). pw[h*512 + dist]
__global__ void pow_kernel(double* __restrict__ pw) {
    int h = threadIdx.x;
    if (h < 8) {
        double gamma = 1.0 - ldexp(1.0, -5 - h);   // 1 - 2^-(5+h), exact
        double p = 1.0;
        for (int i = 0; i < 512; ++i) { pw[h * 512 + i] = p; p *= gamma; }
    }
}

__global__ void zero_counters(int* __restrict__ ctr) {
    if (threadIdx.x < 8) ctr[threadIdx.x] = 0;
}

// ---------------------------------------------------------------------------
// fp32 GEMM + BN (unchanged from R8): 128x128 tile, 8x8 acc, BK=16.
__global__ __launch_bounds__(256, 2) void gemm_bn_f32(
    const float* __restrict__ A, const float* __restrict__ W,
    const float* __restrict__ bias,
    const float* __restrict__ bnw, const float* __restrict__ bnb,
    const float* __restrict__ bnm, const float* __restrict__ bnv,
    float* __restrict__ out)
{
    const int K = 512;
    __shared__ float As[128][20];
    __shared__ float Ws[128][20];

    const int tid = threadIdx.x;
    const int m0 = blockIdx.x * 128;
    const int d0 = blockIdx.y * 128;
    const int srow = tid >> 1;
    const int scol = (tid & 1) << 3;
    const int tm = tid >> 4;
    const int td = tid & 15;

    float acc[8][8];
    #pragma unroll
    for (int i = 0; i < 8; ++i)
        #pragma unroll
        for (int j = 0; j < 8; ++j) acc[i][j] = 0.0f;

    const float* ap = A + (size_t)(m0 + srow) * K + scol;
    const float* wp = W + (size_t)(d0 + srow) * K + scol;

    float4 pa0 = *(const float4*)(ap);
    float4 pa1 = *(const float4*)(ap + 4);
    float4 pw0 = *(const float4*)(wp);
    float4 pw1 = *(const float4*)(wp + 4);

    for (int k0 = 0; k0 < K; k0 += 16) {
        *(float4*)&As[srow][scol]     = pa0;
        *(float4*)&As[srow][scol + 4] = pa1;
        *(float4*)&Ws[srow][scol]     = pw0;
        *(float4*)&Ws[srow][scol + 4] = pw1;
        __syncthreads();

        if (k0 + 16 < K) {
            pa0 = *(const float4*)(ap + k0 + 16);
            pa1 = *(const float4*)(ap + k0 + 20);
            pw0 = *(const float4*)(wp + k0 + 16);
            pw1 = *(const float4*)(wp + k0 + 20);
        }

        #pragma unroll
        for (int kg = 0; kg < 4; ++kg) {
            float4 av[8], wv[8];
            #pragma unroll
            for (int i = 0; i < 8; ++i)
                av[i] = *(const float4*)&As[tm + 16 * i][kg * 4];
            #pragma unroll
            for (int j = 0; j < 8; ++j)
                wv[j] = *(const float4*)&Ws[td + 16 * j][kg * 4];
            #pragma unroll
            for (int i = 0; i < 8; ++i)
                #pragma unroll
                for (int j = 0; j < 8; ++j) {
                    acc[i][j] = fmaf(av[i].x, wv[j].x, acc[i][j]);
                    acc[i][j] = fmaf(av[i].y, wv[j].y, acc[i][j]);
                    acc[i][j] = fmaf(av[i].z, wv[j].z, acc[i][j]);
                    acc[i][j] = fmaf(av[i].w, wv[j].w, acc[i][j]);
                }
        }
        __syncthreads();
    }

    #pragma unroll
    for (int j = 0; j < 8; ++j) {
        int d = d0 + td + 16 * j;
        double inv = (double)bnw[d] / sqrt((double)bnv[d] + 1e-5);
        double sh  = (double)bnb[d] - (double)bnm[d] * inv;
        double bs  = (double)bias[d];
        #pragma unroll
        for (int i = 0; i < 8; ++i) {
            int m = m0 + tm + 16 * i;
            out[(size_t)m * 512 + d] = (float)(((double)acc[i][j] + bs) * inv + sh);
        }
    }
}

// ---------------------------------------------------------------------------
// LIF (v_th=1.0) + mask + margin flag (unchanged).
__global__ void lif_mask_flag(const float* __restrict__ Y, u64* __restrict__ msk,
                              int* __restrict__ ctr, int* __restrict__ list, int slot) {
    int g = blockIdx.x * TPB + threadIdx.x;
    int c = g & 511, n = (g >> 9) & 511, b = g >> 18;
    int h = c >> 6;
    int lane = threadIdx.x & 63;
    double v = 0.0;
    bool flag = false;
    for (int t = 0; t < 4; ++t) {
        float y = Y[((size_t)((t * 8 + b) * 512 + n) << 9) + c];
        double hh = v + ((double)y - v) * 0.5;
        flag |= fabs(hh - 1.0) < MARGIN;
        bool s = hh >= 1.0;
        u64 mk = __ballot(s);
        if (lane == 0) msk[((t * 8 + b) * 8 + h) * 512 + n] = mk;
        v = s ? 0.0 : hh;
    }
    if (flag) {
        int idx = atomicAdd(ctr + slot, 1);
        if (idx < FCAP) list[idx] = g;
    }
}

// ---------------------------------------------------------------------------
// Exact fp64 repair of flagged branch neurons (unchanged).
__global__ void fix_mask(const float* __restrict__ x, const float* __restrict__ w,
                         const float* __restrict__ bias,
                         const float* __restrict__ bnw, const float* __restrict__ bnb,
                         const float* __restrict__ bnm, const float* __restrict__ bnv,
                         u64* __restrict__ msk, const int* __restrict__ ctr,
                         const int* __restrict__ list, int slot) {
    int cnt = ctr[slot]; if (cnt > FCAP) cnt = FCAP;
    int wv = (blockIdx.x * blockDim.x + threadIdx.x) >> 6;
    int nw = (gridDim.x * blockDim.x) >> 6;
    int lane = threadIdx.x & 63;
    for (int i = wv; i < cnt; i += nw) {
        int g = list[i];
        int c = g & 511, n = (g >> 9) & 511, b = g >> 18;
        int h = c >> 6;
        const float* wr = w + (size_t)c * 512;
        double dot[4];
        #pragma unroll
        for (int t = 0; t < 4; ++t) {
            const float* xr = x + ((size_t)((t * 8 + b) * 512 + n) << 9);
            double p = 0.0;
            #pragma unroll
            for (int j = 0; j < 8; ++j)
                p += (double)xr[lane + 64 * j] * (double)wr[lane + 64 * j];
            dot[t] = p;
        }
        #pragma unroll
        for (int off = 32; off; off >>= 1) {
            #pragma unroll
            for (int t = 0; t < 4; ++t)
                dot[t] += __shfl_xor(dot[t], off, 64);
        }
        if (lane == 0) {
            double inv = (double)bnw[c] / sqrt((double)bnv[c] + 1e-5);
            double sh  = (double)bnb[c] - (double)bnm[c] * inv;
            double bs  = (double)bias[c];
            double v = 0.0;
            u64 bit = 1ull << (c & 63);
            for (int t = 0; t < 4; ++t) {
                double y = (dot[t] + bs) * inv + sh;
                double hh = v + (y - v) * 0.5;
                bool s = hh >= 1.0;
                u64* wp_ = &msk[((t * 8 + b) * 8 + h) * 512 + n];
                if (s) atomicOr(wp_, bit); else atomicAnd(wp_, ~bit);
                v = s ? 0.0 : hh;
            }
        }
    }
}

// ---------------------------------------------------------------------------
// Retention via bidirectional linear recurrence.
// One wave per (dir, t, b, h): lane = d, u[64] = fp64 state over e.
//   fwd: u[e] += gamma^{-n} * (k_e & v_d); out_f[n] = gamma^{n} * sum_e q_e u[e]
//   bwd: out first (m>n terms), then inject with weight gamma^{n}.
// All terms >= 0 -> no cancellation; fp32 partial storage error <= 2.5e-7 rel,
// covered by lif_ret's relative margin + repair_ret exact recompute.
__global__ __launch_bounds__(64) void ret_scan(
    const u64* __restrict__ qm, const u64* __restrict__ km,
    const u64* __restrict__ vm, float* __restrict__ accF,
    float* __restrict__ accB, int useAtomic)
{
    int bid = blockIdx.x;              // 512 = dir(2) * t(4)*b(8)*h(8)
    int dir = bid >> 8;
    int tbh = bid & 255;
    int h = tbh & 7, b = (tbh >> 3) & 7, t = tbh >> 6;
    int lane = threadIdx.x;            // d

    int base = ((t * 8 + b) * 8 + h) * 512;
    const u64* qp = qm + base;
    const u64* kp = km + base;
    const u64* vp = vm + base;

    double gamma = 1.0 - ldexp(1.0, -5 - h);
    double invg  = 1.0 / gamma;
    double wInj, wOut;
    if (dir == 0) { wInj = 1.0; wOut = 1.0; }
    else {
        double g511 = 1.0;
        for (int i = 0; i < 511; ++i) g511 *= gamma;
        wInj = g511;           // gamma^n at n=511
        wOut = 1.0 / g511;     // gamma^{-n} at n=511
    }
    const double fInj = invg;                      // both dirs: *= 1/gamma
    const double fOut = gamma;                     // both dirs: *= gamma

    double u[64];
    #pragma unroll
    for (int e = 0; e < 64; ++e) u[e] = 0.0;

    size_t obase = (((size_t)((t * 8 + b) * 512)) << 9) + h * 64 + lane;
    float* outBuf = (dir && !useAtomic) ? accB : accF;

    int r0 = dir ? 511 - lane : lane;
    u64 qc = qp[r0], kc = kp[r0], vc = vp[r0];

    for (int c = 0; c < 8; ++c) {
        u64 qn2 = 0, kn2 = 0, vn2 = 0;
        if (c < 7) {
            int ri = dir ? 511 - ((c + 1) * 64 + lane) : (c + 1) * 64 + lane;
            qn2 = qp[ri]; kn2 = kp[ri]; vn2 = vp[ri];
        }
        #pragma unroll 1
        for (int mm = 0; mm < 64; ++mm) {
            int i = c * 64 + mm;
            int n = dir ? 511 - i : i;
            unsigned ql = __builtin_amdgcn_readlane((unsigned)qc, mm);
            unsigned qh = __builtin_amdgcn_readlane((unsigned)(qc >> 32), mm);
            unsigned kl = __builtin_amdgcn_readlane((unsigned)kc, mm);
            unsigned kh = __builtin_amdgcn_readlane((unsigned)(kc >> 32), mm);
            unsigned vl = __builtin_amdgcn_readlane((unsigned)vc, mm);
            unsigned vh = __builtin_amdgcn_readlane((unsigned)(vc >> 32), mm);
            u64 qw = ((u64)qh << 32) | ql;     // uniform -> SGPR
            u64 kw = ((u64)kh << 32) | kl;
            u64 vw = ((u64)vh << 32) | vl;

            double vm1 = ((vw >> lane) & 1ull) ? 1.0 : 0.0;   // per-lane
            double wv = wInj * vm1;
            double o = 0.0;

            if (dir == 0) {
                #pragma unroll
                for (int e = 0; e < 64; ++e) {
                    double kf = ((kw >> e) & 1ull) ? 1.0 : 0.0;   // uniform
                    u[e] = fma(wv, kf, u[e]);
                }
                #pragma unroll
                for (int e = 0; e < 64; ++e) {
                    double qf = ((qw >> e) & 1ull) ? 1.0 : 0.0;
                    o = fma(u[e], qf, o);
                }
                float val = (float)(o * wOut);
                size_t ix = obase + ((size_t)n << 9);
                if (useAtomic) atomicAdd(&accF[ix], val);
                else outBuf[ix] = val;
            } else {
                #pragma unroll
                for (int e = 0; e < 64; ++e) {
                    double qf = ((qw >> e) & 1ull) ? 1.0 : 0.0;
                    o = fma(u[e], qf, o);
                }
                float val = (float)(o * wOut);
                size_t ix = obase + ((size_t)n << 9);
                if (useAtomic) atomicAdd(&accF[ix], val);
                else outBuf[ix] = val;
                #pragma unroll
                for (int e = 0; e < 64; ++e) {
                    double kf = ((kw >> e) & 1ull) ? 1.0 : 0.0;
                    u[e] = fma(wv, kf, u[e]);
                }
            }
            wInj *= fInj; wOut *= fOut;
        }
        qc = qn2; kc = kn2; vc = vn2;
    }
}

// ---------------------------------------------------------------------------
// Retention LIF (v_th=0.5) over fp32 partial sums; relative-margin flag.
__global__ void lif_ret(const float* __restrict__ aF, const float* __restrict__ aB,
                        int hasB, float* __restrict__ r,
                        int* __restrict__ ctr, int* __restrict__ list) {
    int g = blockIdx.x * TPB + threadIdx.x;
    int c = g & 511, n = (g >> 9) & 511, b = g >> 18;
    double v = 0.0, eb = 0.0;
    bool flag = false;
    for (int t = 0; t < 4; ++t) {
        size_t idx = ((size_t)((t * 8 + b) * 512 + n) << 9) + c;
        double tot = (double)aF[idx];
        if (hasB) tot += (double)aB[idx];
        double x = tot * 0.125;
        double hh = v + (x - v) * 0.5;
        eb = 0.5 * (eb + fabs(x) * 4e-7);
        flag |= fabs(hh - 0.5) <= eb + 1e-12;
        bool s = hh >= 0.5;
        r[idx] = s ? 1.0f : 0.0f;
        v = s ? 0.0 : hh;
        if (s) eb = 0.0;
    }
    if (flag) {
        int idx2 = atomicAdd(ctr + 3, 1);
        if (idx2 < FCAP) list[idx2] = g;
    }
}

// Exact fp64 recompute of flagged retention neurons (gated gamma-sum).
__global__ void repair_ret(const u64* __restrict__ qm, const u64* __restrict__ km,
                           const u64* __restrict__ vm, const double* __restrict__ pw,
                           const int* __restrict__ ctr, const int* __restrict__ list,
                           float* __restrict__ r) {
    int cnt = ctr[3]; if (cnt > FCAP) cnt = FCAP;
    int wv = (blockIdx.x * blockDim.x + threadIdx.x) >> 6;
    int nw = (gridDim.x * blockDim.x) >> 6;
    int lane = threadIdx.x & 63;
    for (int i = wv; i < cnt; i += nw) {
        int g = list[i];
        int c = g & 511, n = (g >> 9) & 511, b = g >> 18;
        int h = c >> 6, d = c & 63;
        double acc_t[4];
        for (int t = 0; t < 4; ++t) {
            int base = ((t * 8 + b) * 8 + h) * 512;
            u64 qw = qm[base + n];
            double p = 0.0;
            for (int j = 0; j < 8; ++j) {
                int m = j * 64 + lane;
                u64 kk = km[base + m];
                u64 vv = vm[base + m];
                if ((vv >> d) & 1ull) {
                    int dist = n - m; if (dist < 0) dist = -dist;
                    p += (double)__popcll(qw & kk) * pw[h * 512 + dist];
                }
            }
            acc_t[t] = p;
        }
        #pragma unroll
        for (int off = 32; off; off >>= 1) {
            #pragma unroll
            for (int t = 0; t < 4; ++t) acc_t[t] += __shfl_xor(acc_t[t], off, 64);
        }
        if (lane == 0) {
            double v = 0.0;
            for (int t = 0; t < 4; ++t) {
                double x = acc_t[t] * 0.125;
                double hh = v + (x - v) * 0.5;
                bool s = hh >= 0.5;
                r[((size_t)((t * 8 + b) * 512 + n) << 9) + c] = s ? 1.0f : 0.0f;
                v = s ? 0.0 : hh;
            }
        }
    }
}

// ---------------------------------------------------------------------------
// Final branch: flag (slot 4), exact fix, provisional write, scatter.
__global__ void final_flag(const float* __restrict__ Y, int* __restrict__ ctr,
                           int* __restrict__ list) {
    int g = blockIdx.x * TPB + threadIdx.x;
    int c = g & 511, n = (g >> 9) & 511, b = g >> 18;
    double v = 0.0;
    bool flag = false;
    for (int t = 0; t < 4; ++t) {
        float y = Y[((size_t)((t * 8 + b) * 512 + n) << 9) + c];
        double hh = v + ((double)y - v) * 0.5;
        flag |= fabs(hh - 1.0) < MARGIN;
        bool s = hh >= 1.0;
        v = s ? 0.0 : hh;
    }
    if (flag) {
        int idx = atomicAdd(ctr + 4, 1);
        if (idx < FCAP) list[idx] = g;
    }
}

__global__ void fix_final(const float* __restrict__ rr, const float* __restrict__ w,
                          const float* __restrict__ bias,
                          const float* __restrict__ bnw, const float* __restrict__ bnb,
                          const float* __restrict__ bnm, const float* __restrict__ bnv,
                          const int* __restrict__ ctr, int* __restrict__ list) {
    int cnt = ctr[4]; if (cnt > FCAP) cnt = FCAP;
    int wv = (blockIdx.x * blockDim.x + threadIdx.x) >> 6;
    int nw = (gridDim.x * blockDim.x) >> 6;
    int lane = threadIdx.x & 63;
    for (int i = wv; i < cnt; i += nw) {
        int g = list[i] & 0x00FFFFFF;
        int c = g & 511, n = (g >> 9) & 511, b = g >> 18;
        const float* wr = w + (size_t)c * 512;
        double dot[4];
        #pragma unroll
        for (int t = 0; t < 4; ++t) {
            const float* xr = rr + ((size_t)((t * 8 + b) * 512 + n) << 9);
            double p = 0.0;
            #pragma unroll
            for (int j = 0; j < 8; ++j)
                p += (double)xr[lane + 64 * j] * (double)wr[lane + 64 * j];
            dot[t] = p;
        }
        #pragma unroll
        for (int off = 32; off; off >>= 1) {
            #pragma unroll
            for (int t = 0; t < 4; ++t)
                dot[t] += __shfl_xor(dot[t], off, 64);
        }
        if (lane == 0) {
            double inv = (double)bnw[c] / sqrt((double)bnv[c] + 1e-5);
            double sh  = (double)bnb[c] - (double)bnm[c] * inv;
            double bs  = (double)bias[c];
            double v = 0.0;
            int sp = 0;
            for (int t = 0; t < 4; ++t) {
                double y = (dot[t] + bs) * inv + sh;
                double hh = v + (y - v) * 0.5;
                bool s = hh >= 1.0;
                sp |= (s ? 1 : 0) << t;
                v = s ? 0.0 : hh;
            }
            list[i] = g | (sp << 24);
        }
    }
}

__global__ void final_write(const float* __restrict__ Y, float* __restrict__ out) {
    int g = blockIdx.x * TPB + threadIdx.x;
    int c = g & 511, n = (g >> 9) & 511, b = g >> 18;
    double v = 0.0;
    for (int t = 0; t < 4; ++t) {
        size_t idx = ((size_t)((t * 8 + b) * 512 + n) << 9) + c;
        float y = Y[idx];
        double hh = v + ((double)y - v) * 0.5;
        bool s = hh >= 1.0;
        out[idx] = s ? 1.0f : 0.0f;
        v = s ? 0.0 : hh;
    }
}

__global__ void fix_scatter(const int* __restrict__ ctr, const int* __restrict__ list,
                            float* __restrict__ out) {
    int cnt = ctr[4]; if (cnt > FCAP) cnt = FCAP;
    int i = blockIdx.x * blockDim.x + threadIdx.x;
    if (i >= cnt) return;
    int e = list[i];
    int g = e & 0x00FFFFFF, sp = (e >> 24) & 0xF;
    int c = g & 511, n = (g >> 9) & 511, b = g >> 18;
    for (int t = 0; t < 4; ++t)
        out[((size_t)((t * 8 + b) * 512 + n) << 9) + c] = ((sp >> t) & 1) ? 1.0f : 0.0f;
}

// ---------------------------------------------------------------------------
extern "C" void kernel_launch(void* const* d_in, const int* in_sizes, int n_in,
                              void* d_out, int out_size, void* d_ws, size_t ws_size,
                              hipStream_t stream) {
    const float* x = (const float*)d_in[0];
    const float *w[4], *bi[4], *bnw[4], *bnb[4], *bnm[4], *bnv[4];
    for (int br = 0; br < 4; ++br) {
        int base = 1 + br * 6;
        w[br]   = (const float*)d_in[base + 0];
        bi[br]  = (const float*)d_in[base + 1];
        bnw[br] = (const float*)d_in[base + 2];
        bnb[br] = (const float*)d_in[base + 3];
        bnm[br] = (const float*)d_in[base + 4];
        bnv[br] = (const float*)d_in[base + 5];
    }

    char* p0 = (char*)d_ws;
    char* p = p0;
    double* pw = (double*)p;  p += 8 * 512 * sizeof(double);      // 32 KB
    u64* qm = (u64*)p;        p += 131072 * sizeof(u64);          // 1 MB
    u64* km = (u64*)p;        p += 131072 * sizeof(u64);          // 1 MB
    u64* vm = (u64*)p;        p += 131072 * sizeof(u64);          // 1 MB
    int* ctr = (int*)p;       p += 1024;
    int* list = (int*)p;      p += (size_t)FCAP * sizeof(int);    // 4 MB
    float* Y = (float*)p;     p += (size_t)16384 * 512 * 4;       // 33.5 MB
    float* accB = (float*)p;  p += (size_t)16384 * 512 * 4;       // 33.5 MB (optional)
    size_t need = (size_t)(p - p0);
    int hasB = (ws_size >= need) ? 1 : 0;
    float* r = (float*)d_out;  // retention spikes staged in d_out

    zero_counters<<<1, 64, 0, stream>>>(ctr);
    pow_kernel<<<1, 64, 0, stream>>>(pw);

    dim3 gg(128, 4);
    // q
    gemm_bn_f32<<<gg, 256, 0, stream>>>(x, w[0], bi[0], bnw[0], bnb[0], bnm[0], bnv[0], Y);
    lif_mask_flag<<<8192, TPB, 0, stream>>>(Y, qm, ctr, list, 0);
    fix_mask<<<128, 256, 0, stream>>>(x, w[0], bi[0], bnw[0], bnb[0], bnm[0], bnv[0], qm, ctr, list, 0);
    // k
    gemm_bn_f32<<<gg, 256, 0, stream>>>(x, w[1], bi[1], bnw[1], bnb[1], bnm[1], bnv[1], Y);
    lif_mask_flag<<<8192, TPB, 0, stream>>>(Y, km, ctr, list, 1);
    fix_mask<<<128, 256, 0, stream>>>(x, w[1], bi[1], bnw[1], bnb[1], bnm[1], bnv[1], km, ctr, list, 1);
    // v
    gemm_bn_f32<<<gg, 256, 0, stream>>>(x, w[2], bi[2], bnw[2], bnb[2], bnm[2], bnv[2], Y);
    lif_mask_flag<<<8192, TPB, 0, stream>>>(Y, vm, ctr, list, 2);
    fix_mask<<<128, 256, 0, stream>>>(x, w[2], bi[2], bnw[2], bnb[2], bnm[2], bnv[2], vm, ctr, list, 2);

    // retention: bidirectional scan -> fp32 partials -> LIF + margin repair
    if (!hasB)
        hipMemsetAsync(Y, 0, (size_t)16384 * 512 * 4, stream);
    ret_scan<<<512, 64, 0, stream>>>(qm, km, vm, Y, accB, hasB ? 0 : 1);
    lif_ret<<<8192, TPB, 0, stream>>>(Y, accB, hasB, r, ctr, list);
    repair_ret<<<256, 256, 0, stream>>>(qm, km, vm, pw, ctr, list, r);

    // p projection (fp32) + flag/fix/write/scatter
    gemm_bn_f32<<<gg, 256, 0, stream>>>(r, w[3], bi[3], bnw[3], bnb[3], bnm[3], bnv[3], Y);
    final_flag<<<8192, TPB, 0, stream>>>(Y, ctr, list);
    fix_final<<<128, 256, 0, stream>>>(r, w[3], bi[3], bnw[3], bnb[3], bnm[3], bnv[3], ctr, list);
    final_write<<<8192, TPB, 0, stream>>>(Y, (float*)d_out);
    fix_scatter<<<4096, 256, 0, stream>>>(ctr, list, (float*)d_out);
}

// Round 10
// 567.519 us; speedup vs baseline: 2.2047x; 2.2047x over previous
//
#include <hip/hip_runtime.h>
#include <cstdint>

typedef unsigned long long u64;

#define TPB 256
#define MARGIN 5e-4
#define FCAP (1 << 20)

typedef __bf16 bf16x8 __attribute__((ext_vector_type(8)));
typedef __bf16 bf16x4 __attribute__((ext_vector_type(4)));
typedef float f32x4 __attribute__((ext_vector_type(4)));

// ---------------------------------------------------------------------------
// gamma^dist table, fp64. pw[h*512 + dist]
__global__ void pow_kernel(double* __restrict__ pw) {
    int h = threadIdx.x;
    if (h < 8) {
        double gamma = 1.0 - ldexp(1.0, -5 - h);
        double p = 1.0;
        for (int i = 0; i < 512; ++i) { pw[h * 512 + i] = p; p *= gamma; }
    }
}

__global__ void zero_counters(int* __restrict__ ctr) {
    if (threadIdx.x < 8) ctr[threadIdx.x] = 0;
}

// ---------------------------------------------------------------------------
// Split-bf16 MFMA GEMM + BN.  out[m,d] = BN( sum_c A[m,c]*W[d,c] + bias[d] ).
// a = hi + lo (RN bf16 each); 3 products hh+hl+lh -> |err| <~ 1.7e-4 < MARGIN,
// covered by lif flag + exact fp64 repair.  Block tile 128m x 64d, 4 waves
// (2x2), wave tile 64x32 = 4x2 fragments of 16x16, K-step 32.
__global__ __launch_bounds__(256) void gemm_bn_mfma(
    const float* __restrict__ A, const float* __restrict__ W,
    const float* __restrict__ bias,
    const float* __restrict__ bnw, const float* __restrict__ bnb,
    const float* __restrict__ bnm, const float* __restrict__ bnv,
    float* __restrict__ out)
{
    __shared__ __bf16 Ah[128][36];   // 36-short rows: b64 frag reads <=4-way
    __shared__ __bf16 Al[128][36];
    __shared__ __bf16 Wh[64][36];
    __shared__ __bf16 Wl[64][36];

    const int tid = threadIdx.x;
    const int m0 = blockIdx.x * 128;
    const int d0 = blockIdx.y * 64;
    const int wv = tid >> 6;
    const int wm = wv >> 1;          // 0..1
    const int wd = wv & 1;           // 0..1
    const int lane = tid & 63;
    const int fr = lane & 15;
    const int fg = lane >> 4;        // k-group

    const int srow = tid >> 3;       // 0..31
    const int scol = (tid & 7) * 4;  // 0,4,..,28

    f32x4 acc[4][2];
    #pragma unroll
    for (int i = 0; i < 4; ++i)
        #pragma unroll
        for (int j = 0; j < 2; ++j)
            acc[i][j] = (f32x4){0.f, 0.f, 0.f, 0.f};

    for (int k0 = 0; k0 < 512; k0 += 32) {
        __syncthreads();
        // stage A: 128x32 fp32 -> bf16 hi/lo
        #pragma unroll
        for (int rep = 0; rep < 4; ++rep) {
            int row = srow + 32 * rep;
            float4 va = *(const float4*)(A + (size_t)(m0 + row) * 512 + k0 + scol);
            #pragma unroll
            for (int e = 0; e < 4; ++e) {
                float f = (&va.x)[e];
                __bf16 h = (__bf16)f;
                __bf16 l = (__bf16)(f - (float)h);
                Ah[row][scol + e] = h;
                Al[row][scol + e] = l;
            }
        }
        // stage W: 64x32
        #pragma unroll
        for (int rep = 0; rep < 2; ++rep) {
            int row = srow + 32 * rep;
            float4 vw = *(const float4*)(W + (size_t)(d0 + row) * 512 + k0 + scol);
            #pragma unroll
            for (int e = 0; e < 4; ++e) {
                float f = (&vw.x)[e];
                __bf16 h = (__bf16)f;
                __bf16 l = (__bf16)(f - (float)h);
                Wh[row][scol + e] = h;
                Wl[row][scol + e] = l;
            }
        }
        __syncthreads();

        union FU { bf16x8 v8; struct { bf16x4 a, b; } s; };
        bf16x8 ah[4], al[4], bh[2], bl[2];
        #pragma unroll
        for (int i = 0; i < 4; ++i) {
            int row = wm * 64 + i * 16 + fr;
            FU u1, u2;
            u1.s.a = *(const bf16x4*)&Ah[row][fg * 8];
            u1.s.b = *(const bf16x4*)&Ah[row][fg * 8 + 4];
            u2.s.a = *(const bf16x4*)&Al[row][fg * 8];
            u2.s.b = *(const bf16x4*)&Al[row][fg * 8 + 4];
            ah[i] = u1.v8; al[i] = u2.v8;
        }
        #pragma unroll
        for (int j = 0; j < 2; ++j) {
            int row = wd * 32 + j * 16 + fr;
            FU u1, u2;
            u1.s.a = *(const bf16x4*)&Wh[row][fg * 8];
            u1.s.b = *(const bf16x4*)&Wh[row][fg * 8 + 4];
            u2.s.a = *(const bf16x4*)&Wl[row][fg * 8];
            u2.s.b = *(const bf16x4*)&Wl[row][fg * 8 + 4];
            bh[j] = u1.v8; bl[j] = u2.v8;
        }
        #pragma unroll
        for (int i = 0; i < 4; ++i)
            #pragma unroll
            for (int j = 0; j < 2; ++j) {
                acc[i][j] = __builtin_amdgcn_mfma_f32_16x16x32_bf16(ah[i], bh[j], acc[i][j], 0, 0, 0);
                acc[i][j] = __builtin_amdgcn_mfma_f32_16x16x32_bf16(ah[i], bl[j], acc[i][j], 0, 0, 0);
                acc[i][j] = __builtin_amdgcn_mfma_f32_16x16x32_bf16(al[i], bh[j], acc[i][j], 0, 0, 0);
            }
    }

    // epilogue: C/D layout col = lane&15, row = (lane>>4)*4 + reg
    #pragma unroll
    for (int j = 0; j < 2; ++j) {
        int d = d0 + wd * 32 + j * 16 + fr;
        double inv = (double)bnw[d] / sqrt((double)bnv[d] + 1e-5);
        double sh  = (double)bnb[d] - (double)bnm[d] * inv;
        double bs  = (double)bias[d];
        #pragma unroll
        for (int i = 0; i < 4; ++i) {
            #pragma unroll
            for (int reg = 0; reg < 4; ++reg) {
                int m = m0 + wm * 64 + i * 16 + fg * 4 + reg;
                out[(size_t)m * 512 + d] = (float)(((double)acc[i][j][reg] + bs) * inv + sh);
            }
        }
    }
}

// ---------------------------------------------------------------------------
// LIF (v_th=1.0) + mask + margin flag.
__global__ void lif_mask_flag(const float* __restrict__ Y, u64* __restrict__ msk,
                              int* __restrict__ ctr, int* __restrict__ list, int slot) {
    int g = blockIdx.x * TPB + threadIdx.x;
    int c = g & 511, n = (g >> 9) & 511, b = g >> 18;
    int h = c >> 6;
    int lane = threadIdx.x & 63;
    double v = 0.0;
    bool flag = false;
    for (int t = 0; t < 4; ++t) {
        float y = Y[((size_t)((t * 8 + b) * 512 + n) << 9) + c];
        double hh = v + ((double)y - v) * 0.5;
        flag |= fabs(hh - 1.0) < MARGIN;
        bool s = hh >= 1.0;
        u64 mk = __ballot(s);
        if (lane == 0) msk[((t * 8 + b) * 8 + h) * 512 + n] = mk;
        v = s ? 0.0 : hh;
    }
    if (flag) {
        int idx = atomicAdd(ctr + slot, 1);
        if (idx < FCAP) list[idx] = g;
    }
}

// ---------------------------------------------------------------------------
// Exact fp64 repair of flagged branch neurons.
__global__ void fix_mask(const float* __restrict__ x, const float* __restrict__ w,
                         const float* __restrict__ bias,
                         const float* __restrict__ bnw, const float* __restrict__ bnb,
                         const float* __restrict__ bnm, const float* __restrict__ bnv,
                         u64* __restrict__ msk, const int* __restrict__ ctr,
                         const int* __restrict__ list, int slot) {
    int cnt = ctr[slot]; if (cnt > FCAP) cnt = FCAP;
    int wv = (blockIdx.x * blockDim.x + threadIdx.x) >> 6;
    int nw = (gridDim.x * blockDim.x) >> 6;
    int lane = threadIdx.x & 63;
    for (int i = wv; i < cnt; i += nw) {
        int g = list[i];
        int c = g & 511, n = (g >> 9) & 511, b = g >> 18;
        int h = c >> 6;
        const float* wr = w + (size_t)c * 512;
        double dot[4];
        #pragma unroll
        for (int t = 0; t < 4; ++t) {
            const float* xr = x + ((size_t)((t * 8 + b) * 512 + n) << 9);
            double p = 0.0;
            #pragma unroll
            for (int j = 0; j < 8; ++j)
                p += (double)xr[lane + 64 * j] * (double)wr[lane + 64 * j];
            dot[t] = p;
        }
        #pragma unroll
        for (int off = 32; off; off >>= 1) {
            #pragma unroll
            for (int t = 0; t < 4; ++t)
                dot[t] += __shfl_xor(dot[t], off, 64);
        }
        if (lane == 0) {
            double inv = (double)bnw[c] / sqrt((double)bnv[c] + 1e-5);
            double sh  = (double)bnb[c] - (double)bnm[c] * inv;
            double bs  = (double)bias[c];
            double v = 0.0;
            u64 bit = 1ull << (c & 63);
            for (int t = 0; t < 4; ++t) {
                double y = (dot[t] + bs) * inv + sh;
                double hh = v + (y - v) * 0.5;
                bool s = hh >= 1.0;
                u64* wp_ = &msk[((t * 8 + b) * 8 + h) * 512 + n];
                if (s) atomicOr(wp_, bit); else atomicAnd(wp_, ~bit);
                v = s ? 0.0 : hh;
            }
        }
    }
}

// ---------------------------------------------------------------------------
// Retention + retention LIF, exact fp64 (proven R7/R8 version, 318 us).
#define NMASK 6
__global__ __launch_bounds__(512) void retention6(
    const u64* __restrict__ qm, const u64* __restrict__ km,
    const u64* __restrict__ vm, const double* __restrict__ pw,
    float* __restrict__ r)
{
    int bid = blockIdx.x;            // 1024 = b(8)*h(8)*ng(8)*dh(2)
    int dh = bid & 1;
    int ng = (bid >> 1) & 7;
    int h  = (bid >> 4) & 7;
    int b  = bid >> 7;
    int wid  = threadIdx.x >> 6;
    int t    = wid & 3;
    int mh   = wid >> 2;
    int lane = threadIdx.x & 63;
    int n = ng * 64 + lane;

    __shared__ double pw_s[512];
    __shared__ double comb[4][64][17];
    double* vs_s = &comb[0][0][0];

    if (threadIdx.x < 512) pw_s[threadIdx.x] = pw[h * 512 + threadIdx.x];
    __syncthreads();

    int base = ((t * 8 + b) * 8 + h) * 512;
    u64 qn = qm[base + n];
    const u64* kp = km + base + mh * 256;
    const u64* vp = vm + base + mh * 256;
    int msta = mh * 256;

    double acc[32];
    #pragma unroll
    for (int dd = 0; dd < 32; ++dd) acc[dd] = 0.0;

    u64 kcur = kp[lane];
    u64 vcur = vp[lane];
    #pragma unroll 1
    for (int c = 0; c < 4; ++c) {
        u64 knxt = 0, vnxt = 0;
        if (c < 3) {
            knxt = kp[(c + 1) * 64 + lane];
            vnxt = vp[(c + 1) * 64 + lane];
        }
        unsigned vsel = dh ? (unsigned)(vcur >> 32) : (unsigned)vcur;
        int mbase = msta + c * 64;
        #pragma unroll 4
        for (int mm = 0; mm < 64; ++mm) {
            unsigned kl = __builtin_amdgcn_readlane((unsigned)kcur, mm);
            unsigned kh = __builtin_amdgcn_readlane((unsigned)(kcur >> 32), mm);
            unsigned vv_s = __builtin_amdgcn_readlane(vsel, mm);
            u64 kv = ((u64)kh << 32) | kl;
            int m = mbase + mm;
            int dist = n - m; if (dist < 0) dist = -dist;
            double w = (double)__popcll(qn & kv) * pw_s[dist];
            u64 wbits = __builtin_bit_cast(u64, w);

            unsigned vv_v;
            asm("v_mov_b32 %0, %1" : "=v"(vv_v) : "s"(vv_s));
            #pragma unroll
            for (int dd = 0; dd < NMASK; ++dd) {
                unsigned mk = (unsigned)(((int)(vv_v << (31 - dd))) >> 31);
                u64 gw = (((u64)mk << 32) | mk) & wbits;
                acc[dd] += __builtin_bit_cast(double, gw);
            }
            #pragma unroll
            for (int dd = NMASK; dd < 32; ++dd)
                acc[dd] = fma(w, ((vv_s >> dd) & 1u) ? 1.0 : 0.0, acc[dd]);
        }
        kcur = knxt; vcur = vnxt;
    }

    __syncthreads();
    if (mh == 1) {
        #pragma unroll
        for (int dd = 0; dd < 16; ++dd) comb[t][lane][dd] = acc[dd];
    }
    __syncthreads();
    if (mh == 0) {
        #pragma unroll
        for (int dd = 0; dd < 16; ++dd) acc[dd] += comb[t][lane][dd];
    }
    __syncthreads();
    if (mh == 1) {
        #pragma unroll
        for (int dd = 16; dd < 32; ++dd) comb[t][lane][dd - 16] = acc[dd];
    }
    __syncthreads();
    if (mh == 0) {
        #pragma unroll
        for (int dd = 16; dd < 32; ++dd) acc[dd] += comb[t][lane][dd - 16];
    }
    __syncthreads();

    for (int tt = 0; tt < 4; ++tt) {
        if (tt == t && mh == 0) {
            size_t rbase = ((size_t)((t * 8 + b) * 512 + n) << 9) + h * 64 + dh * 32;
            #pragma unroll
            for (int dd = 0; dd < 32; ++dd) {
                int sw = lane * 33 + dd;
                double v = (t == 0) ? 0.0 : vs_s[sw];
                double x = acc[dd] * 0.125;
                double hh = v + (x - v) * 0.5;
                bool s = hh >= 0.5;
                r[rbase + dd] = s ? 1.0f : 0.0f;
                if (t < 3) vs_s[sw] = s ? 0.0 : hh;
            }
        }
        __syncthreads();
    }
}

// ---------------------------------------------------------------------------
// Final branch: flag (slot 3), exact fix, provisional write, scatter.
__global__ void final_flag(const float* __restrict__ Y, int* __restrict__ ctr,
                           int* __restrict__ list) {
    int g = blockIdx.x * TPB + threadIdx.x;
    int c = g & 511, n = (g >> 9) & 511, b = g >> 18;
    double v = 0.0;
    bool flag = false;
    for (int t = 0; t < 4; ++t) {
        float y = Y[((size_t)((t * 8 + b) * 512 + n) << 9) + c];
        double hh = v + ((double)y - v) * 0.5;
        flag |= fabs(hh - 1.0) < MARGIN;
        bool s = hh >= 1.0;
        v = s ? 0.0 : hh;
    }
    if (flag) {
        int idx = atomicAdd(ctr + 3, 1);
        if (idx < FCAP) list[idx] = g;
    }
}

__global__ void fix_final(const float* __restrict__ rr, const float* __restrict__ w,
                          const float* __restrict__ bias,
                          const float* __restrict__ bnw, const float* __restrict__ bnb,
                          const float* __restrict__ bnm, const float* __restrict__ bnv,
                          const int* __restrict__ ctr, int* __restrict__ list) {
    int cnt = ctr[3]; if (cnt > FCAP) cnt = FCAP;
    int wv = (blockIdx.x * blockDim.x + threadIdx.x) >> 6;
    int nw = (gridDim.x * blockDim.x) >> 6;
    int lane = threadIdx.x & 63;
    for (int i = wv; i < cnt; i += nw) {
        int g = list[i] & 0x00FFFFFF;
        int c = g & 511, n = (g >> 9) & 511, b = g >> 18;
        const float* wr = w + (size_t)c * 512;
        double dot[4];
        #pragma unroll
        for (int t = 0; t < 4; ++t) {
            const float* xr = rr + ((size_t)((t * 8 + b) * 512 + n) << 9);
            double p = 0.0;
            #pragma unroll
            for (int j = 0; j < 8; ++j)
                p += (double)xr[lane + 64 * j] * (double)wr[lane + 64 * j];
            dot[t] = p;
        }
        #pragma unroll
        for (int off = 32; off; off >>= 1) {
            #pragma unroll
            for (int t = 0; t < 4; ++t)
                dot[t] += __shfl_xor(dot[t], off, 64);
        }
        if (lane == 0) {
            double inv = (double)bnw[c] / sqrt((double)bnv[c] + 1e-5);
            double sh  = (double)bnb[c] - (double)bnm[c] * inv;
            double bs  = (double)bias[c];
            double v = 0.0;
            int sp = 0;
            for (int t = 0; t < 4; ++t) {
                double y = (dot[t] + bs) * inv + sh;
                double hh = v + (y - v) * 0.5;
                bool s = hh >= 1.0;
                sp |= (s ? 1 : 0) << t;
                v = s ? 0.0 : hh;
            }
            list[i] = g | (sp << 24);
        }
    }
}

__global__ void final_write(const float* __restrict__ Y, float* __restrict__ out) {
    int g = blockIdx.x * TPB + threadIdx.x;
    int c = g & 511, n = (g >> 9) & 511, b = g >> 18;
    double v = 0.0;
    for (int t = 0; t < 4; ++t) {
        size_t idx = ((size_t)((t * 8 + b) * 512 + n) << 9) + c;
        float y = Y[idx];
        double hh = v + ((double)y - v) * 0.5;
        bool s = hh >= 1.0;
        out[idx] = s ? 1.0f : 0.0f;
        v = s ? 0.0 : hh;
    }
}

__global__ void fix_scatter(const int* __restrict__ ctr, const int* __restrict__ list,
                            float* __restrict__ out) {
    int cnt = ctr[3]; if (cnt > FCAP) cnt = FCAP;
    int i = blockIdx.x * blockDim.x + threadIdx.x;
    if (i >= cnt) return;
    int e = list[i];
    int g = e & 0x00FFFFFF, sp = (e >> 24) & 0xF;
    int c = g & 511, n = (g >> 9) & 511, b = g >> 18;
    for (int t = 0; t < 4; ++t)
        out[((size_t)((t * 8 + b) * 512 + n) << 9) + c] = ((sp >> t) & 1) ? 1.0f : 0.0f;
}

// ---------------------------------------------------------------------------
extern "C" void kernel_launch(void* const* d_in, const int* in_sizes, int n_in,
                              void* d_out, int out_size, void* d_ws, size_t ws_size,
                              hipStream_t stream) {
    const float* x = (const float*)d_in[0];
    const float *w[4], *bi[4], *bnw[4], *bnb[4], *bnm[4], *bnv[4];
    for (int br = 0; br < 4; ++br) {
        int base = 1 + br * 6;
        w[br]   = (const float*)d_in[base + 0];
        bi[br]  = (const float*)d_in[base + 1];
        bnw[br] = (const float*)d_in[base + 2];
        bnb[br] = (const float*)d_in[base + 3];
        bnm[br] = (const float*)d_in[base + 4];
        bnv[br] = (const float*)d_in[base + 5];
    }

    char* p = (char*)d_ws;
    double* pw = (double*)p;  p += 8 * 512 * sizeof(double);      // 32 KB
    u64* qm = (u64*)p;        p += 131072 * sizeof(u64);          // 1 MB
    u64* km = (u64*)p;        p += 131072 * sizeof(u64);          // 1 MB
    u64* vm = (u64*)p;        p += 131072 * sizeof(u64);          // 1 MB
    int* ctr = (int*)p;       p += 1024;
    int* list = (int*)p;      p += (size_t)FCAP * sizeof(int);    // 4 MB
    float* Y = (float*)p;     p += (size_t)16384 * 512 * 4;       // 33.5 MB
    float* r = (float*)d_out;  // retention spikes staged in d_out

    zero_counters<<<1, 64, 0, stream>>>(ctr);
    pow_kernel<<<1, 64, 0, stream>>>(pw);

    dim3 gg(128, 8);
    // q
    gemm_bn_mfma<<<gg, 256, 0, stream>>>(x, w[0], bi[0], bnw[0], bnb[0], bnm[0], bnv[0], Y);
    lif_mask_flag<<<8192, TPB, 0, stream>>>(Y, qm, ctr, list, 0);
    fix_mask<<<128, 256, 0, stream>>>(x, w[0], bi[0], bnw[0], bnb[0], bnm[0], bnv[0], qm, ctr, list, 0);
    // k
    gemm_bn_mfma<<<gg, 256, 0, stream>>>(x, w[1], bi[1], bnw[1], bnb[1], bnm[1], bnv[1], Y);
    lif_mask_flag<<<8192, TPB, 0, stream>>>(Y, km, ctr, list, 1);
    fix_mask<<<128, 256, 0, stream>>>(x, w[1], bi[1], bnw[1], bnb[1], bnm[1], bnv[1], km, ctr, list, 1);
    // v
    gemm_bn_mfma<<<gg, 256, 0, stream>>>(x, w[2], bi[2], bnw[2], bnb[2], bnm[2], bnv[2], Y);
    lif_mask_flag<<<8192, TPB, 0, stream>>>(Y, vm, ctr, list, 2);
    fix_mask<<<128, 256, 0, stream>>>(x, w[2], bi[2], bnw[2], bnb[2], bnm[2], bnv[2], vm, ctr, list, 2);

    // retention (exact fp64) -> r in d_out
    retention6<<<1024, 512, 0, stream>>>(qm, km, vm, pw, r);

    // p projection (split-bf16 MFMA) + flag/fix/write/scatter
    gemm_bn_mfma<<<gg, 256, 0, stream>>>(r, w[3], bi[3], bnw[3], bnb[3], bnm[3], bnv[3], Y);
    final_flag<<<8192, TPB, 0, stream>>>(Y, ctr, list);
    fix_final<<<128, 256, 0, stream>>>(r, w[3], bi[3], bnw[3], bnb[3], bnm[3], bnv[3], ctr, list);
    final_write<<<8192, TPB, 0, stream>>>(Y, (float*)d_out);
    fix_scatter<<<4096, 256, 0, stream>>>(ctr, list, (float*)d_out);
}

// Round 12
// 388.593 us; speedup vs baseline: 3.2198x; 1.4604x over previous
//
#include <hip/hip_runtime.h>
#include <cstdint>

typedef unsigned long long u64;

#define TPB 256
#define MARGIN 5e-4
#define FCAP (1 << 20)

typedef __bf16 bf16x8 __attribute__((ext_vector_type(8)));
typedef float f32x4 __attribute__((ext_vector_type(4)));

// ---------------------------------------------------------------------------
// gamma^dist table, fp64. pw[h*512 + dist]
__global__ void pow_kernel(double* __restrict__ pw) {
    int h = threadIdx.x;
    if (h < 8) {
        double gamma = 1.0 - ldexp(1.0, -5 - h);
        double p = 1.0;
        for (int i = 0; i < 512; ++i) { pw[h * 512 + i] = p; p *= gamma; }
    }
}

__global__ void zero_counters(int* __restrict__ ctr) {
    if (threadIdx.x < 8) ctr[threadIdx.x] = 0;
}

// ---------------------------------------------------------------------------
// Split-bf16 MFMA GEMM + BN (proven R10). 128m x 64d block, 4 waves.
__global__ __launch_bounds__(256) void gemm_bn_mfma(
    const float* __restrict__ A, const float* __restrict__ W,
    const float* __restrict__ bias,
    const float* __restrict__ bnw, const float* __restrict__ bnb,
    const float* __restrict__ bnm, const float* __restrict__ bnv,
    float* __restrict__ out)
{
    __shared__ __bf16 Ah[128][36];
    __shared__ __bf16 Al[128][36];
    __shared__ __bf16 Wh[64][36];
    __shared__ __bf16 Wl[64][36];

    const int tid = threadIdx.x;
    const int m0 = blockIdx.x * 128;
    const int d0 = blockIdx.y * 64;
    const int wv = tid >> 6;
    const int wm = wv >> 1;
    const int wd = wv & 1;
    const int lane = tid & 63;
    const int fr = lane & 15;
    const int fg = lane >> 4;

    const int srow = tid >> 3;
    const int scol = (tid & 7) * 4;

    f32x4 acc[4][2];
    #pragma unroll
    for (int i = 0; i < 4; ++i)
        #pragma unroll
        for (int j = 0; j < 2; ++j)
            acc[i][j] = (f32x4){0.f, 0.f, 0.f, 0.f};

    for (int k0 = 0; k0 < 512; k0 += 32) {
        __syncthreads();
        #pragma unroll
        for (int rep = 0; rep < 4; ++rep) {
            int row = srow + 32 * rep;
            float4 va = *(const float4*)(A + (size_t)(m0 + row) * 512 + k0 + scol);
            #pragma unroll
            for (int e = 0; e < 4; ++e) {
                float f = (&va.x)[e];
                __bf16 h = (__bf16)f;
                __bf16 l = (__bf16)(f - (float)h);
                Ah[row][scol + e] = h;
                Al[row][scol + e] = l;
            }
        }
        #pragma unroll
        for (int rep = 0; rep < 2; ++rep) {
            int row = srow + 32 * rep;
            float4 vw = *(const float4*)(W + (size_t)(d0 + row) * 512 + k0 + scol);
            #pragma unroll
            for (int e = 0; e < 4; ++e) {
                float f = (&vw.x)[e];
                __bf16 h = (__bf16)f;
                __bf16 l = (__bf16)(f - (float)h);
                Wh[row][scol + e] = h;
                Wl[row][scol + e] = l;
            }
        }
        __syncthreads();

        union FU { bf16x8 v8; struct { __bf16 a[4], b[4]; } s; };
        bf16x8 ah[4], al[4], bh[2], bl[2];
        #pragma unroll
        for (int i = 0; i < 4; ++i) {
            int row = wm * 64 + i * 16 + fr;
            FU u1, u2;
            *(double*)&u1.s.a[0] = *(const double*)&Ah[row][fg * 8];
            *(double*)&u1.s.b[0] = *(const double*)&Ah[row][fg * 8 + 4];
            *(double*)&u2.s.a[0] = *(const double*)&Al[row][fg * 8];
            *(double*)&u2.s.b[0] = *(const double*)&Al[row][fg * 8 + 4];
            ah[i] = u1.v8; al[i] = u2.v8;
        }
        #pragma unroll
        for (int j = 0; j < 2; ++j) {
            int row = wd * 32 + j * 16 + fr;
            FU u1, u2;
            *(double*)&u1.s.a[0] = *(const double*)&Wh[row][fg * 8];
            *(double*)&u1.s.b[0] = *(const double*)&Wh[row][fg * 8 + 4];
            *(double*)&u2.s.a[0] = *(const double*)&Wl[row][fg * 8];
            *(double*)&u2.s.b[0] = *(const double*)&Wl[row][fg * 8 + 4];
            bh[j] = u1.v8; bl[j] = u2.v8;
        }
        #pragma unroll
        for (int i = 0; i < 4; ++i)
            #pragma unroll
            for (int j = 0; j < 2; ++j) {
                acc[i][j] = __builtin_amdgcn_mfma_f32_16x16x32_bf16(ah[i], bh[j], acc[i][j], 0, 0, 0);
                acc[i][j] = __builtin_amdgcn_mfma_f32_16x16x32_bf16(ah[i], bl[j], acc[i][j], 0, 0, 0);
                acc[i][j] = __builtin_amdgcn_mfma_f32_16x16x32_bf16(al[i], bh[j], acc[i][j], 0, 0, 0);
            }
    }

    #pragma unroll
    for (int j = 0; j < 2; ++j) {
        int d = d0 + wd * 32 + j * 16 + fr;
        double inv = (double)bnw[d] / sqrt((double)bnv[d] + 1e-5);
        double sh  = (double)bnb[d] - (double)bnm[d] * inv;
        double bs  = (double)bias[d];
        #pragma unroll
        for (int i = 0; i < 4; ++i) {
            #pragma unroll
            for (int reg = 0; reg < 4; ++reg) {
                int m = m0 + wm * 64 + i * 16 + fg * 4 + reg;
                out[(size_t)m * 512 + d] = (float)(((double)acc[i][j][reg] + bs) * inv + sh);
            }
        }
    }
}

// ---------------------------------------------------------------------------
// LIF (v_th=1.0) + mask + margin flag.
__global__ void lif_mask_flag(const float* __restrict__ Y, u64* __restrict__ msk,
                              int* __restrict__ ctr, int* __restrict__ list, int slot) {
    int g = blockIdx.x * TPB + threadIdx.x;
    int c = g & 511, n = (g >> 9) & 511, b = g >> 18;
    int h = c >> 6;
    int lane = threadIdx.x & 63;
    double v = 0.0;
    bool flag = false;
    for (int t = 0; t < 4; ++t) {
        float y = Y[((size_t)((t * 8 + b) * 512 + n) << 9) + c];
        double hh = v + ((double)y - v) * 0.5;
        flag |= fabs(hh - 1.0) < MARGIN;
        bool s = hh >= 1.0;
        u64 mk = __ballot(s);
        if (lane == 0) msk[((t * 8 + b) * 8 + h) * 512 + n] = mk;
        v = s ? 0.0 : hh;
    }
    if (flag) {
        int idx = atomicAdd(ctr + slot, 1);
        if (idx < FCAP) list[idx] = g;
    }
}

// ---------------------------------------------------------------------------
// Exact fp64 repair of flagged branch neurons.
__global__ void fix_mask(const float* __restrict__ x, const float* __restrict__ w,
                         const float* __restrict__ bias,
                         const float* __restrict__ bnw, const float* __restrict__ bnb,
                         const float* __restrict__ bnm, const float* __restrict__ bnv,
                         u64* __restrict__ msk, const int* __restrict__ ctr,
                         const int* __restrict__ list, int slot) {
    int cnt = ctr[slot]; if (cnt > FCAP) cnt = FCAP;
    int wv = (blockIdx.x * blockDim.x + threadIdx.x) >> 6;
    int nw = (gridDim.x * blockDim.x) >> 6;
    int lane = threadIdx.x & 63;
    for (int i = wv; i < cnt; i += nw) {
        int g = list[i];
        int c = g & 511, n = (g >> 9) & 511, b = g >> 18;
        int h = c >> 6;
        const float* wr = w + (size_t)c * 512;
        double dot[4];
        #pragma unroll
        for (int t = 0; t < 4; ++t) {
            const float* xr = x + ((size_t)((t * 8 + b) * 512 + n) << 9);
            double p = 0.0;
            #pragma unroll
            for (int j = 0; j < 8; ++j)
                p += (double)xr[lane + 64 * j] * (double)wr[lane + 64 * j];
            dot[t] = p;
        }
        #pragma unroll
        for (int off = 32; off; off >>= 1) {
            #pragma unroll
            for (int t = 0; t < 4; ++t)
                dot[t] += __shfl_xor(dot[t], off, 64);
        }
        if (lane == 0) {
            double inv = (double)bnw[c] / sqrt((double)bnv[c] + 1e-5);
            double sh  = (double)bnb[c] - (double)bnm[c] * inv;
            double bs  = (double)bias[c];
            double v = 0.0;
            u64 bit = 1ull << (c & 63);
            for (int t = 0; t < 4; ++t) {
                double y = (dot[t] + bs) * inv + sh;
                double hh = v + (y - v) * 0.5;
                bool s = hh >= 1.0;
                u64* wp_ = &msk[((t * 8 + b) * 8 + h) * 512 + n];
                if (s) atomicOr(wp_, bit); else atomicAnd(wp_, ~bit);
                v = s ? 0.0 : hh;
            }
        }
    }
}

// ---------------------------------------------------------------------------
// Fused retention: per block one (t,b,h) x 64-row n-tile.  Loop over 8
// m-chunks: S = q@k^T (exact MFMA) -> scale gamma^dist/8 -> split bf16 hi/lo
// (per-wave LDS redistribution) -> PV MFMA accumulate.  No global A.
__global__ __launch_bounds__(256) void ret_fused(
    const u64* __restrict__ qm, const u64* __restrict__ km,
    const u64* __restrict__ vm, const double* __restrict__ pw,
    float* __restrict__ O)
{
    int bid = blockIdx.x;          // 2048 = tbh(256) * ntile(8)
    int tbh = bid >> 3;
    int n0 = (bid & 7) * 64;
    int h = tbh & 7;
    int tb = tbh >> 3;             // t*8+b
    int tid = threadIdx.x;
    int wv = tid >> 6, lane = tid & 63, fr = lane & 15, fg = lane >> 4;
    int wn = wv * 16;

    __shared__ __bf16 Qs[64][72];
    __shared__ __bf16 Ks[64][72];
    __shared__ __bf16 VsT[64][72];     // [d][m-in-chunk]
    __shared__ __bf16 Sh[4][16][72];   // per-wave S hi
    __shared__ __bf16 Sl[4][16][72];   // per-wave S lo
    __shared__ u64 vmc[64];
    __shared__ float pwf[512];         // gamma^dist / 8

    int base = tbh * 512;

    for (int i = tid; i < 512; i += 256) pwf[i] = (float)pw[h * 512 + i] * 0.125f;

    {   // stage Q (64 n x 64 e), 4 threads/row
        int row = tid >> 2, q4 = (tid & 3) * 16;
        u64 qw = qm[base + n0 + row];
        #pragma unroll
        for (int s = 0; s < 4; ++s) {
            int e0 = q4 + s * 4;
            u64 pq = 0;
            #pragma unroll
            for (int e = 0; e < 4; ++e)
                if ((qw >> (e0 + e)) & 1ull) pq |= 0x3F80ull << (16 * e);
            *(u64*)&Qs[row][e0] = pq;
        }
    }

    f32x4 acc_o[4];
    #pragma unroll
    for (int j = 0; j < 4; ++j) acc_o[j] = (f32x4){0.f, 0.f, 0.f, 0.f};

    for (int mc = 0; mc < 8; ++mc) {
        __syncthreads();   // prior chunk's Ks/VsT reads done (Qs staged, mc=0)
        {   // stage K chunk (64 m x 64 e)
            int row = tid >> 2, q4 = (tid & 3) * 16;
            u64 kw = km[base + mc * 64 + row];
            #pragma unroll
            for (int s = 0; s < 4; ++s) {
                int e0 = q4 + s * 4;
                u64 pk = 0;
                #pragma unroll
                for (int e = 0; e < 4; ++e)
                    if ((kw >> (e0 + e)) & 1ull) pk |= 0x3F80ull << (16 * e);
                *(u64*)&Ks[row][e0] = pk;
            }
        }
        if (tid < 64) vmc[tid] = vm[base + mc * 64 + tid];
        __syncthreads();   // Ks, vmc visible
        {   // transpose-pack V^T: VsT[d][m]
            int d = tid >> 2, mg = (tid & 3) * 16;
            #pragma unroll
            for (int s4 = 0; s4 < 4; ++s4) {
                u64 pk = 0;
                #pragma unroll
                for (int e = 0; e < 4; ++e)
                    if ((vmc[mg + s4 * 4 + e] >> d) & 1ull) pk |= 0x3F80ull << (16 * e);
                *(u64*)&VsT[d][mg + s4 * 4] = pk;
            }
        }
        // QK: S tile 16n x 64m, K=64 (e)
        f32x4 acc_s[4];
        #pragma unroll
        for (int j = 0; j < 4; ++j) acc_s[j] = (f32x4){0.f, 0.f, 0.f, 0.f};
        #pragma unroll
        for (int ks = 0; ks < 2; ++ks) {
            bf16x8 qa = *(const bf16x8*)&Qs[wn + fr][ks * 32 + fg * 8];
            bf16x8 kb[4];
            #pragma unroll
            for (int j = 0; j < 4; ++j)
                kb[j] = *(const bf16x8*)&Ks[j * 16 + fr][ks * 32 + fg * 8];
            #pragma unroll
            for (int j = 0; j < 4; ++j)
                acc_s[j] = __builtin_amdgcn_mfma_f32_16x16x32_bf16(qa, kb[j], acc_s[j], 0, 0, 0);
        }
        __syncthreads();   // VsT visible to all waves
        // scale + split S -> per-wave LDS (C-layout -> A-layout redistribution)
        #pragma unroll
        for (int j = 0; j < 4; ++j) {
            #pragma unroll
            for (int reg = 0; reg < 4; ++reg) {
                int nl = fg * 4 + reg;
                int ng = n0 + wn + nl;
                int mg = mc * 64 + j * 16 + fr;
                int dist = ng - mg; if (dist < 0) dist = -dist;
                float a = acc_s[j][reg] * pwf[dist];
                __bf16 hp = (__bf16)a;
                __bf16 lp = (__bf16)(a - (float)hp);
                Sh[wv][nl][j * 16 + fr] = hp;
                Sl[wv][nl][j * 16 + fr] = lp;
            }
        }
        __syncthreads();   // S buffers ready
        // PV: acc_o += (Sh+Sl) @ V^T, K=64 (m)
        #pragma unroll
        for (int ks = 0; ks < 2; ++ks) {
            bf16x8 af = *(const bf16x8*)&Sh[wv][fr][ks * 32 + fg * 8];
            bf16x8 al = *(const bf16x8*)&Sl[wv][fr][ks * 32 + fg * 8];
            bf16x8 vb[4];
            #pragma unroll
            for (int j = 0; j < 4; ++j)
                vb[j] = *(const bf16x8*)&VsT[j * 16 + fr][ks * 32 + fg * 8];
            #pragma unroll
            for (int j = 0; j < 4; ++j) {
                acc_o[j] = __builtin_amdgcn_mfma_f32_16x16x32_bf16(af, vb[j], acc_o[j], 0, 0, 0);
                acc_o[j] = __builtin_amdgcn_mfma_f32_16x16x32_bf16(al, vb[j], acc_o[j], 0, 0, 0);
            }
        }
    }

    #pragma unroll
    for (int j = 0; j < 4; ++j) {
        int c = h * 64 + j * 16 + fr;
        #pragma unroll
        for (int reg = 0; reg < 4; ++reg) {
            int n = n0 + wn + fg * 4 + reg;
            O[((size_t)(tb * 512 + n) << 9) + c] = acc_o[j][reg];
        }
    }
}

// ---------------------------------------------------------------------------
// Retention LIF (v_th=0.5) in-place on O (= d_out); relative-margin flag.
__global__ void lif_ret(float* __restrict__ OR, int* __restrict__ ctr,
                        int* __restrict__ list) {
    int g = blockIdx.x * TPB + threadIdx.x;
    int c = g & 511, n = (g >> 9) & 511, b = g >> 18;
    double v = 0.0, eb = 0.0;
    bool flag = false;
    for (int t = 0; t < 4; ++t) {
        size_t idx = ((size_t)((t * 8 + b) * 512 + n) << 9) + c;
        double x = (double)OR[idx];
        double hh = v + (x - v) * 0.5;
        eb = 0.5 * eb + 0.5 * (fabs(x) * 1e-4);
        flag |= fabs(hh - 0.5) <= eb + 1e-9;
        bool s = hh >= 0.5;
        OR[idx] = s ? 1.0f : 0.0f;
        v = s ? 0.0 : hh;
        if (s) eb = 0.0;
    }
    if (flag) {
        int i2 = atomicAdd(ctr + 4, 1);
        if (i2 < FCAP) list[i2] = g;
    }
}

// Exact fp64 recompute of flagged retention neurons (gated gamma-sum).
__global__ void repair_ret(const u64* __restrict__ qm, const u64* __restrict__ km,
                           const u64* __restrict__ vm, const double* __restrict__ pw,
                           const int* __restrict__ ctr, const int* __restrict__ list,
                           float* __restrict__ r) {
    int cnt = ctr[4]; if (cnt > FCAP) cnt = FCAP;
    int wv = (blockIdx.x * blockDim.x + threadIdx.x) >> 6;
    int nw = (gridDim.x * blockDim.x) >> 6;
    int lane = threadIdx.x & 63;
    for (int i = wv; i < cnt; i += nw) {
        int g = list[i];
        int c = g & 511, n = (g >> 9) & 511, b = g >> 18;
        int h = c >> 6, d = c & 63;
        double acc_t[4];
        for (int t = 0; t < 4; ++t) {
            int base = ((t * 8 + b) * 8 + h) * 512;
            u64 qw = qm[base + n];
            double p = 0.0;
            for (int j = 0; j < 8; ++j) {
                int m = j * 64 + lane;
                u64 kk = km[base + m];
                u64 vv = vm[base + m];
                if ((vv >> d) & 1ull) {
                    int dist = n - m; if (dist < 0) dist = -dist;
                    p += (double)__popcll(qw & kk) * pw[h * 512 + dist];
                }
            }
            acc_t[t] = p;
        }
        #pragma unroll
        for (int off = 32; off; off >>= 1) {
            #pragma unroll
            for (int t = 0; t < 4; ++t) acc_t[t] += __shfl_xor(acc_t[t], off, 64);
        }
        if (lane == 0) {
            double v = 0.0;
            for (int t = 0; t < 4; ++t) {
                double x = acc_t[t] * 0.125;
                double hh = v + (x - v) * 0.5;
                bool s = hh >= 0.5;
                r[((size_t)((t * 8 + b) * 512 + n) << 9) + c] = s ? 1.0f : 0.0f;
                v = s ? 0.0 : hh;
            }
        }
    }
}

// ---------------------------------------------------------------------------
// Final branch: flag (slot 3), exact fix, provisional write, scatter.
__global__ void final_flag(const float* __restrict__ Y, int* __restrict__ ctr,
                           int* __restrict__ list) {
    int g = blockIdx.x * TPB + threadIdx.x;
    int c = g & 511, n = (g >> 9) & 511, b = g >> 18;
    double v = 0.0;
    bool flag = false;
    for (int t = 0; t < 4; ++t) {
        float y = Y[((size_t)((t * 8 + b) * 512 + n) << 9) + c];
        double hh = v + ((double)y - v) * 0.5;
        flag |= fabs(hh - 1.0) < MARGIN;
        bool s = hh >= 1.0;
        v = s ? 0.0 : hh;
    }
    if (flag) {
        int idx = atomicAdd(ctr + 3, 1);
        if (idx < FCAP) list[idx] = g;
    }
}

__global__ void fix_final(const float* __restrict__ rr, const float* __restrict__ w,
                          const float* __restrict__ bias,
                          const float* __restrict__ bnw, const float* __restrict__ bnb,
                          const float* __restrict__ bnm, const float* __restrict__ bnv,
                          const int* __restrict__ ctr, int* __restrict__ list) {
    int cnt = ctr[3]; if (cnt > FCAP) cnt = FCAP;
    int wv = (blockIdx.x * blockDim.x + threadIdx.x) >> 6;
    int nw = (gridDim.x * blockDim.x) >> 6;
    int lane = threadIdx.x & 63;
    for (int i = wv; i < cnt; i += nw) {
        int g = list[i] & 0x00FFFFFF;
        int c = g & 511, n = (g >> 9) & 511, b = g >> 18;
        const float* wr = w + (size_t)c * 512;
        double dot[4];
        #pragma unroll
        for (int t = 0; t < 4; ++t) {
            const float* xr = rr + ((size_t)((t * 8 + b) * 512 + n) << 9);
            double p = 0.0;
            #pragma unroll
            for (int j = 0; j < 8; ++j)
                p += (double)xr[lane + 64 * j] * (double)wr[lane + 64 * j];
            dot[t] = p;
        }
        #pragma unroll
        for (int off = 32; off; off >>= 1) {
            #pragma unroll
            for (int t = 0; t < 4; ++t)
                dot[t] += __shfl_xor(dot[t], off, 64);
        }
        if (lane == 0) {
            double inv = (double)bnw[c] / sqrt((double)bnv[c] + 1e-5);
            double sh  = (double)bnb[c] - (double)bnm[c] * inv;
            double bs  = (double)bias[c];
            double v = 0.0;
            int sp = 0;
            for (int t = 0; t < 4; ++t) {
                double y = (dot[t] + bs) * inv + sh;
                double hh = v + (y - v) * 0.5;
                bool s = hh >= 1.0;
                sp |= (s ? 1 : 0) << t;
                v = s ? 0.0 : hh;
            }
            list[i] = g | (sp << 24);
        }
    }
}

__global__ void final_write(const float* __restrict__ Y, float* __restrict__ out) {
    int g = blockIdx.x * TPB + threadIdx.x;
    int c = g & 511, n = (g >> 9) & 511, b = g >> 18;
    double v = 0.0;
    for (int t = 0; t < 4; ++t) {
        size_t idx = ((size_t)((t * 8 + b) * 512 + n) << 9) + c;
        float y = Y[idx];
        double hh = v + ((double)y - v) * 0.5;
        bool s = hh >= 1.0;
        out[idx] = s ? 1.0f : 0.0f;
        v = s ? 0.0 : hh;
    }
}

__global__ void fix_scatter(const int* __restrict__ ctr, const int* __restrict__ list,
                            float* __restrict__ out) {
    int cnt = ctr[3]; if (cnt > FCAP) cnt = FCAP;
    int i = blockIdx.x * blockDim.x + threadIdx.x;
    if (i >= cnt) return;
    int e = list[i];
    int g = e & 0x00FFFFFF, sp = (e >> 24) & 0xF;
    int c = g & 511, n = (g >> 9) & 511, b = g >> 18;
    for (int t = 0; t < 4; ++t)
        out[((size_t)((t * 8 + b) * 512 + n) << 9) + c] = ((sp >> t) & 1) ? 1.0f : 0.0f;
}

// ---------------------------------------------------------------------------
extern "C" void kernel_launch(void* const* d_in, const int* in_sizes, int n_in,
                              void* d_out, int out_size, void* d_ws, size_t ws_size,
                              hipStream_t stream) {
    const float* x = (const float*)d_in[0];
    const float *w[4], *bi[4], *bnw[4], *bnb[4], *bnm[4], *bnv[4];
    for (int br = 0; br < 4; ++br) {
        int base = 1 + br * 6;
        w[br]   = (const float*)d_in[base + 0];
        bi[br]  = (const float*)d_in[base + 1];
        bnw[br] = (const float*)d_in[base + 2];
        bnb[br] = (const float*)d_in[base + 3];
        bnm[br] = (const float*)d_in[base + 4];
        bnv[br] = (const float*)d_in[base + 5];
    }

    char* p = (char*)d_ws;
    double* pw = (double*)p;  p += 8 * 512 * sizeof(double);      // 32 KB
    u64* qm = (u64*)p;        p += 131072 * sizeof(u64);          // 1 MB
    u64* km = (u64*)p;        p += 131072 * sizeof(u64);          // 1 MB
    u64* vm = (u64*)p;        p += 131072 * sizeof(u64);          // 1 MB
    int* ctr = (int*)p;       p += 1024;
    int* list = (int*)p;      p += (size_t)FCAP * sizeof(int);    // 4 MB
    float* Y = (float*)p;     p += (size_t)16384 * 512 * 4;       // 32 MiB
    float* r = (float*)d_out;  // O, then retention spikes, staged in d_out

    zero_counters<<<1, 64, 0, stream>>>(ctr);
    pow_kernel<<<1, 64, 0, stream>>>(pw);

    dim3 gg(128, 8);
    // q
    gemm_bn_mfma<<<gg, 256, 0, stream>>>(x, w[0], bi[0], bnw[0], bnb[0], bnm[0], bnv[0], Y);
    lif_mask_flag<<<8192, TPB, 0, stream>>>(Y, qm, ctr, list, 0);
    fix_mask<<<128, 256, 0, stream>>>(x, w[0], bi[0], bnw[0], bnb[0], bnm[0], bnv[0], qm, ctr, list, 0);
    // k
    gemm_bn_mfma<<<gg, 256, 0, stream>>>(x, w[1], bi[1], bnw[1], bnb[1], bnm[1], bnv[1], Y);
    lif_mask_flag<<<8192, TPB, 0, stream>>>(Y, km, ctr, list, 1);
    fix_mask<<<128, 256, 0, stream>>>(x, w[1], bi[1], bnw[1], bnb[1], bnm[1], bnv[1], km, ctr, list, 1);
    // v
    gemm_bn_mfma<<<gg, 256, 0, stream>>>(x, w[2], bi[2], bnw[2], bnb[2], bnm[2], bnv[2], Y);
    lif_mask_flag<<<8192, TPB, 0, stream>>>(Y, vm, ctr, list, 2);
    fix_mask<<<128, 256, 0, stream>>>(x, w[2], bi[2], bnw[2], bnb[2], bnm[2], bnv[2], vm, ctr, list, 2);

    // fused retention -> O in d_out -> LIF in place -> exact repair
    ret_fused<<<2048, 256, 0, stream>>>(qm, km, vm, pw, (float*)d_out);
    lif_ret<<<8192, TPB, 0, stream>>>((float*)d_out, ctr, list);
    repair_ret<<<256, 256, 0, stream>>>(qm, km, vm, pw, ctr, list, (float*)d_out);

    // p projection (split-bf16 MFMA, writes Y) + flag/fix/write/scatter
    gemm_bn_mfma<<<gg, 256, 0, stream>>>(r, w[3], bi[3], bnw[3], bnb[3], bnm[3], bnv[3], Y);
    final_flag<<<8192, TPB, 0, stream>>>(Y, ctr, list);
    fix_final<<<128, 256, 0, stream>>>(r, w[3], bi[3], bnw[3], bnb[3], bnm[3], bnv[3], ctr, list);
    final_write<<<8192, TPB, 0, stream>>>(Y, (float*)d_out);
    fix_scatter<<<4096, 256, 0, stream>>>(ctr, list, (float*)d_out);
}

// Round 13
// 365.960 us; speedup vs baseline: 3.4189x; 1.0618x over previous
//
#include <hip/hip_runtime.h>
#include <cstdint>

typedef unsigned long long u64;

#define TPB 256
#define MARGIN 5e-4
#define FCAP (1 << 20)

typedef __bf16 bf16x8 __attribute__((ext_vector_type(8)));
typedef __bf16 bf16x4 __attribute__((ext_vector_type(4)));
typedef float f32x4 __attribute__((ext_vector_type(4)));

// ---------------------------------------------------------------------------
__global__ void pow_kernel(double* __restrict__ pw) {
    int h = threadIdx.x;
    if (h < 8) {
        double gamma = 1.0 - ldexp(1.0, -5 - h);
        double p = 1.0;
        for (int i = 0; i < 512; ++i) { pw[h * 512 + i] = p; p *= gamma; }
    }
}

__global__ void zero_counters(int* __restrict__ ctr) {
    if (threadIdx.x < 8) ctr[threadIdx.x] = 0;
}

// ---------------------------------------------------------------------------
// fp32 -> bf16 hi/lo split (precompute pass).
__global__ void split_f32(const float* __restrict__ in, __bf16* __restrict__ hi,
                          __bf16* __restrict__ lo, int n) {
    int i = (blockIdx.x * 256 + threadIdx.x) * 4;
    if (i >= n) return;
    float4 v = *(const float4*)(in + i);
    bf16x4 h, l;
    #pragma unroll
    for (int e = 0; e < 4; ++e) {
        float f = (&v.x)[e];
        __bf16 hh = (__bf16)f;
        h[e] = hh;
        l[e] = (__bf16)(f - (float)hh);
    }
    *(bf16x4*)(hi + i) = h;
    *(bf16x4*)(lo + i) = l;
}

// fp32 {0,1} -> bf16 (exact), hi only.
__global__ void split_bin(const float* __restrict__ in, __bf16* __restrict__ hi, int n) {
    int i = (blockIdx.x * 256 + threadIdx.x) * 4;
    if (i >= n) return;
    float4 v = *(const float4*)(in + i);
    bf16x4 h;
    #pragma unroll
    for (int e = 0; e < 4; ++e) h[e] = (__bf16)(&v.x)[e];
    *(bf16x4*)(hi + i) = h;
}

// ---------------------------------------------------------------------------
// MFMA GEMM + BN on pre-split bf16 inputs.  128x128 tile, 4 waves (2x2).
// asplit=1: acc = AhBh + AhBl + AlBh (3 passes).  asplit=0: A exact (binary),
// acc = AhBh + AhBl (2 passes).
__global__ __launch_bounds__(256) void gemm_bn_mfma2(
    const __bf16* __restrict__ Ahg, const __bf16* __restrict__ Alg,
    const __bf16* __restrict__ Whg, const __bf16* __restrict__ Wlg,
    const float* __restrict__ bias,
    const float* __restrict__ bnw, const float* __restrict__ bnb,
    const float* __restrict__ bnm, const float* __restrict__ bnv,
    float* __restrict__ out, int asplit)
{
    __shared__ __bf16 AhS[128][40];   // 80B rows: 16B aligned, 2-way banks
    __shared__ __bf16 AlS[128][40];
    __shared__ __bf16 WhS[128][40];
    __shared__ __bf16 WlS[128][40];

    const int tid = threadIdx.x;
    const int m0 = blockIdx.x * 128;
    const int d0 = blockIdx.y * 128;
    const int wv = tid >> 6;
    const int wm = wv >> 1;
    const int wd = wv & 1;
    const int lane = tid & 63;
    const int fr = lane & 15;
    const int fg = lane >> 4;
    const int srow = tid >> 1;
    const int sseg = (tid & 1) * 16;

    f32x4 acc[4][4];
    #pragma unroll
    for (int i = 0; i < 4; ++i)
        #pragma unroll
        for (int j = 0; j < 4; ++j)
            acc[i][j] = (f32x4){0.f, 0.f, 0.f, 0.f};

    for (int k0 = 0; k0 < 512; k0 += 32) {
        __syncthreads();
        {
            const __bf16* pa = Ahg + (size_t)(m0 + srow) * 512 + k0 + sseg;
            *(bf16x8*)&AhS[srow][sseg]     = *(const bf16x8*)pa;
            *(bf16x8*)&AhS[srow][sseg + 8] = *(const bf16x8*)(pa + 8);
            if (asplit) {
                const __bf16* pl = Alg + (size_t)(m0 + srow) * 512 + k0 + sseg;
                *(bf16x8*)&AlS[srow][sseg]     = *(const bf16x8*)pl;
                *(bf16x8*)&AlS[srow][sseg + 8] = *(const bf16x8*)(pl + 8);
            }
            const __bf16* pwh = Whg + (size_t)(d0 + srow) * 512 + k0 + sseg;
            const __bf16* pwl = Wlg + (size_t)(d0 + srow) * 512 + k0 + sseg;
            *(bf16x8*)&WhS[srow][sseg]     = *(const bf16x8*)pwh;
            *(bf16x8*)&WhS[srow][sseg + 8] = *(const bf16x8*)(pwh + 8);
            *(bf16x8*)&WlS[srow][sseg]     = *(const bf16x8*)pwl;
            *(bf16x8*)&WlS[srow][sseg + 8] = *(const bf16x8*)(pwl + 8);
        }
        __syncthreads();

        bf16x8 ah[4], bh[4], bl[4];
        #pragma unroll
        for (int i = 0; i < 4; ++i)
            ah[i] = *(const bf16x8*)&AhS[wm * 64 + i * 16 + fr][fg * 8];
        #pragma unroll
        for (int j = 0; j < 4; ++j) {
            bh[j] = *(const bf16x8*)&WhS[wd * 64 + j * 16 + fr][fg * 8];
            bl[j] = *(const bf16x8*)&WlS[wd * 64 + j * 16 + fr][fg * 8];
        }
        #pragma unroll
        for (int i = 0; i < 4; ++i)
            #pragma unroll
            for (int j = 0; j < 4; ++j) {
                acc[i][j] = __builtin_amdgcn_mfma_f32_16x16x32_bf16(ah[i], bh[j], acc[i][j], 0, 0, 0);
                acc[i][j] = __builtin_amdgcn_mfma_f32_16x16x32_bf16(ah[i], bl[j], acc[i][j], 0, 0, 0);
            }
        if (asplit) {
            bf16x8 al[4];
            #pragma unroll
            for (int i = 0; i < 4; ++i)
                al[i] = *(const bf16x8*)&AlS[wm * 64 + i * 16 + fr][fg * 8];
            #pragma unroll
            for (int i = 0; i < 4; ++i)
                #pragma unroll
                for (int j = 0; j < 4; ++j)
                    acc[i][j] = __builtin_amdgcn_mfma_f32_16x16x32_bf16(al[i], bh[j], acc[i][j], 0, 0, 0);
        }
    }

    #pragma unroll
    for (int j = 0; j < 4; ++j) {
        int d = d0 + wd * 64 + j * 16 + fr;
        double inv = (double)bnw[d] / sqrt((double)bnv[d] + 1e-5);
        double sh  = (double)bnb[d] - (double)bnm[d] * inv;
        double bs  = (double)bias[d];
        #pragma unroll
        for (int i = 0; i < 4; ++i) {
            #pragma unroll
            for (int reg = 0; reg < 4; ++reg) {
                int m = m0 + wm * 64 + i * 16 + fg * 4 + reg;
                out[(size_t)m * 512 + d] = (float)(((double)acc[i][j][reg] + bs) * inv + sh);
            }
        }
    }
}

// ---------------------------------------------------------------------------
// Fallback (R12-proven): fp32-input split-bf16 MFMA GEMM. 128m x 64d block.
__global__ __launch_bounds__(256) void gemm_bn_mfma(
    const float* __restrict__ A, const float* __restrict__ W,
    const float* __restrict__ bias,
    const float* __restrict__ bnw, const float* __restrict__ bnb,
    const float* __restrict__ bnm, const float* __restrict__ bnv,
    float* __restrict__ out)
{
    __shared__ __bf16 Ah[128][36];
    __shared__ __bf16 Al[128][36];
    __shared__ __bf16 Wh[64][36];
    __shared__ __bf16 Wl[64][36];

    const int tid = threadIdx.x;
    const int m0 = blockIdx.x * 128;
    const int d0 = blockIdx.y * 64;
    const int wv = tid >> 6;
    const int wm = wv >> 1;
    const int wd = wv & 1;
    const int lane = tid & 63;
    const int fr = lane & 15;
    const int fg = lane >> 4;
    const int srow = tid >> 3;
    const int scol = (tid & 7) * 4;

    f32x4 acc[4][2];
    #pragma unroll
    for (int i = 0; i < 4; ++i)
        #pragma unroll
        for (int j = 0; j < 2; ++j)
            acc[i][j] = (f32x4){0.f, 0.f, 0.f, 0.f};

    for (int k0 = 0; k0 < 512; k0 += 32) {
        __syncthreads();
        #pragma unroll
        for (int rep = 0; rep < 4; ++rep) {
            int row = srow + 32 * rep;
            float4 va = *(const float4*)(A + (size_t)(m0 + row) * 512 + k0 + scol);
            #pragma unroll
            for (int e = 0; e < 4; ++e) {
                float f = (&va.x)[e];
                __bf16 h = (__bf16)f;
                Ah[row][scol + e] = h;
                Al[row][scol + e] = (__bf16)(f - (float)h);
            }
        }
        #pragma unroll
        for (int rep = 0; rep < 2; ++rep) {
            int row = srow + 32 * rep;
            float4 vw = *(const float4*)(W + (size_t)(d0 + row) * 512 + k0 + scol);
            #pragma unroll
            for (int e = 0; e < 4; ++e) {
                float f = (&vw.x)[e];
                __bf16 h = (__bf16)f;
                Wh[row][scol + e] = h;
                Wl[row][scol + e] = (__bf16)(f - (float)h);
            }
        }
        __syncthreads();

        union FU { bf16x8 v8; struct { __bf16 a[4], b[4]; } s; };
        bf16x8 ah[4], al[4], bh[2], bl[2];
        #pragma unroll
        for (int i = 0; i < 4; ++i) {
            int row = wm * 64 + i * 16 + fr;
            FU u1, u2;
            *(double*)&u1.s.a[0] = *(const double*)&Ah[row][fg * 8];
            *(double*)&u1.s.b[0] = *(const double*)&Ah[row][fg * 8 + 4];
            *(double*)&u2.s.a[0] = *(const double*)&Al[row][fg * 8];
            *(double*)&u2.s.b[0] = *(const double*)&Al[row][fg * 8 + 4];
            ah[i] = u1.v8; al[i] = u2.v8;
        }
        #pragma unroll
        for (int j = 0; j < 2; ++j) {
            int row = wd * 32 + j * 16 + fr;
            FU u1, u2;
            *(double*)&u1.s.a[0] = *(const double*)&Wh[row][fg * 8];
            *(double*)&u1.s.b[0] = *(const double*)&Wh[row][fg * 8 + 4];
            *(double*)&u2.s.a[0] = *(const double*)&Wl[row][fg * 8];
            *(double*)&u2.s.b[0] = *(const double*)&Wl[row][fg * 8 + 4];
            bh[j] = u1.v8; bl[j] = u2.v8;
        }
        #pragma unroll
        for (int i = 0; i < 4; ++i)
            #pragma unroll
            for (int j = 0; j < 2; ++j) {
                acc[i][j] = __builtin_amdgcn_mfma_f32_16x16x32_bf16(ah[i], bh[j], acc[i][j], 0, 0, 0);
                acc[i][j] = __builtin_amdgcn_mfma_f32_16x16x32_bf16(ah[i], bl[j], acc[i][j], 0, 0, 0);
                acc[i][j] = __builtin_amdgcn_mfma_f32_16x16x32_bf16(al[i], bh[j], acc[i][j], 0, 0, 0);
            }
    }

    #pragma unroll
    for (int j = 0; j < 2; ++j) {
        int d = d0 + wd * 32 + j * 16 + fr;
        double inv = (double)bnw[d] / sqrt((double)bnv[d] + 1e-5);
        double sh  = (double)bnb[d] - (double)bnm[d] * inv;
        double bs  = (double)bias[d];
        #pragma unroll
        for (int i = 0; i < 4; ++i) {
            #pragma unroll
            for (int reg = 0; reg < 4; ++reg) {
                int m = m0 + wm * 64 + i * 16 + fg * 4 + reg;
                out[(size_t)m * 512 + d] = (float)(((double)acc[i][j][reg] + bs) * inv + sh);
            }
        }
    }
}

// ---------------------------------------------------------------------------
__global__ void lif_mask_flag(const float* __restrict__ Y, u64* __restrict__ msk,
                              int* __restrict__ ctr, int* __restrict__ list, int slot) {
    int g = blockIdx.x * TPB + threadIdx.x;
    int c = g & 511, n = (g >> 9) & 511, b = g >> 18;
    int h = c >> 6;
    int lane = threadIdx.x & 63;
    double v = 0.0;
    bool flag = false;
    for (int t = 0; t < 4; ++t) {
        float y = Y[((size_t)((t * 8 + b) * 512 + n) << 9) + c];
        double hh = v + ((double)y - v) * 0.5;
        flag |= fabs(hh - 1.0) < MARGIN;
        bool s = hh >= 1.0;
        u64 mk = __ballot(s);
        if (lane == 0) msk[((t * 8 + b) * 8 + h) * 512 + n] = mk;
        v = s ? 0.0 : hh;
    }
    if (flag) {
        int idx = atomicAdd(ctr + slot, 1);
        if (idx < FCAP) list[idx] = g;
    }
}

__global__ void fix_mask(const float* __restrict__ x, const float* __restrict__ w,
                         const float* __restrict__ bias,
                         const float* __restrict__ bnw, const float* __restrict__ bnb,
                         const float* __restrict__ bnm, const float* __restrict__ bnv,
                         u64* __restrict__ msk, const int* __restrict__ ctr,
                         const int* __restrict__ list, int slot) {
    int cnt = ctr[slot]; if (cnt > FCAP) cnt = FCAP;
    int wv = (blockIdx.x * blockDim.x + threadIdx.x) >> 6;
    int nw = (gridDim.x * blockDim.x) >> 6;
    int lane = threadIdx.x & 63;
    for (int i = wv; i < cnt; i += nw) {
        int g = list[i];
        int c = g & 511, n = (g >> 9) & 511, b = g >> 18;
        int h = c >> 6;
        const float* wr = w + (size_t)c * 512;
        double dot[4];
        #pragma unroll
        for (int t = 0; t < 4; ++t) {
            const float* xr = x + ((size_t)((t * 8 + b) * 512 + n) << 9);
            double p = 0.0;
            #pragma unroll
            for (int j = 0; j < 8; ++j)
                p += (double)xr[lane + 64 * j] * (double)wr[lane + 64 * j];
            dot[t] = p;
        }
        #pragma unroll
        for (int off = 32; off; off >>= 1) {
            #pragma unroll
            for (int t = 0; t < 4; ++t)
                dot[t] += __shfl_xor(dot[t], off, 64);
        }
        if (lane == 0) {
            double inv = (double)bnw[c] / sqrt((double)bnv[c] + 1e-5);
            double sh  = (double)bnb[c] - (double)bnm[c] * inv;
            double bs  = (double)bias[c];
            double v = 0.0;
            u64 bit = 1ull << (c & 63);
            for (int t = 0; t < 4; ++t) {
                double y = (dot[t] + bs) * inv + sh;
                double hh = v + (y - v) * 0.5;
                bool s = hh >= 1.0;
                u64* wp_ = &msk[((t * 8 + b) * 8 + h) * 512 + n];
                if (s) atomicOr(wp_, bit); else atomicAnd(wp_, ~bit);
                v = s ? 0.0 : hh;
            }
        }
    }
}

// ---------------------------------------------------------------------------
// Fused retention (R12-proven).
__global__ __launch_bounds__(256) void ret_fused(
    const u64* __restrict__ qm, const u64* __restrict__ km,
    const u64* __restrict__ vm, const double* __restrict__ pw,
    float* __restrict__ O)
{
    int bid = blockIdx.x;
    int tbh = bid >> 3;
    int n0 = (bid & 7) * 64;
    int h = tbh & 7;
    int tb = tbh >> 3;
    int tid = threadIdx.x;
    int wv = tid >> 6, lane = tid & 63, fr = lane & 15, fg = lane >> 4;
    int wn = wv * 16;

    __shared__ __bf16 Qs[64][72];
    __shared__ __bf16 Ks[64][72];
    __shared__ __bf16 VsT[64][72];
    __shared__ __bf16 Sh[4][16][72];
    __shared__ __bf16 Sl[4][16][72];
    __shared__ u64 vmc[64];
    __shared__ float pwf[512];

    int base = tbh * 512;

    for (int i = tid; i < 512; i += 256) pwf[i] = (float)pw[h * 512 + i] * 0.125f;

    {
        int row = tid >> 2, q4 = (tid & 3) * 16;
        u64 qw = qm[base + n0 + row];
        #pragma unroll
        for (int s = 0; s < 4; ++s) {
            int e0 = q4 + s * 4;
            u64 pq = 0;
            #pragma unroll
            for (int e = 0; e < 4; ++e)
                if ((qw >> (e0 + e)) & 1ull) pq |= 0x3F80ull << (16 * e);
            *(u64*)&Qs[row][e0] = pq;
        }
    }

    f32x4 acc_o[4];
    #pragma unroll
    for (int j = 0; j < 4; ++j) acc_o[j] = (f32x4){0.f, 0.f, 0.f, 0.f};

    for (int mc = 0; mc < 8; ++mc) {
        __syncthreads();
        {
            int row = tid >> 2, q4 = (tid & 3) * 16;
            u64 kw = km[base + mc * 64 + row];
            #pragma unroll
            for (int s = 0; s < 4; ++s) {
                int e0 = q4 + s * 4;
                u64 pk = 0;
                #pragma unroll
                for (int e = 0; e < 4; ++e)
                    if ((kw >> (e0 + e)) & 1ull) pk |= 0x3F80ull << (16 * e);
                *(u64*)&Ks[row][e0] = pk;
            }
        }
        if (tid < 64) vmc[tid] = vm[base + mc * 64 + tid];
        __syncthreads();
        {
            int d = tid >> 2, mg = (tid & 3) * 16;
            #pragma unroll
            for (int s4 = 0; s4 < 4; ++s4) {
                u64 pk = 0;
                #pragma unroll
                for (int e = 0; e < 4; ++e)
                    if ((vmc[mg + s4 * 4 + e] >> d) & 1ull) pk |= 0x3F80ull << (16 * e);
                *(u64*)&VsT[d][mg + s4 * 4] = pk;
            }
        }
        f32x4 acc_s[4];
        #pragma unroll
        for (int j = 0; j < 4; ++j) acc_s[j] = (f32x4){0.f, 0.f, 0.f, 0.f};
        #pragma unroll
        for (int ks = 0; ks < 2; ++ks) {
            bf16x8 qa = *(const bf16x8*)&Qs[wn + fr][ks * 32 + fg * 8];
            bf16x8 kb[4];
            #pragma unroll
            for (int j = 0; j < 4; ++j)
                kb[j] = *(const bf16x8*)&Ks[j * 16 + fr][ks * 32 + fg * 8];
            #pragma unroll
            for (int j = 0; j < 4; ++j)
                acc_s[j] = __builtin_amdgcn_mfma_f32_16x16x32_bf16(qa, kb[j], acc_s[j], 0, 0, 0);
        }
        __syncthreads();
        #pragma unroll
        for (int j = 0; j < 4; ++j) {
            #pragma unroll
            for (int reg = 0; reg < 4; ++reg) {
                int nl = fg * 4 + reg;
                int ng = n0 + wn + nl;
                int mg = mc * 64 + j * 16 + fr;
                int dist = ng - mg; if (dist < 0) dist = -dist;
                float a = acc_s[j][reg] * pwf[dist];
                __bf16 hp = (__bf16)a;
                __bf16 lp = (__bf16)(a - (float)hp);
                Sh[wv][nl][j * 16 + fr] = hp;
                Sl[wv][nl][j * 16 + fr] = lp;
            }
        }
        __syncthreads();
        #pragma unroll
        for (int ks = 0; ks < 2; ++ks) {
            bf16x8 af = *(const bf16x8*)&Sh[wv][fr][ks * 32 + fg * 8];
            bf16x8 al = *(const bf16x8*)&Sl[wv][fr][ks * 32 + fg * 8];
            bf16x8 vb[4];
            #pragma unroll
            for (int j = 0; j < 4; ++j)
                vb[j] = *(const bf16x8*)&VsT[j * 16 + fr][ks * 32 + fg * 8];
            #pragma unroll
            for (int j = 0; j < 4; ++j) {
                acc_o[j] = __builtin_amdgcn_mfma_f32_16x16x32_bf16(af, vb[j], acc_o[j], 0, 0, 0);
                acc_o[j] = __builtin_amdgcn_mfma_f32_16x16x32_bf16(al, vb[j], acc_o[j], 0, 0, 0);
            }
        }
    }

    #pragma unroll
    for (int j = 0; j < 4; ++j) {
        int c = h * 64 + j * 16 + fr;
        #pragma unroll
        for (int reg = 0; reg < 4; ++reg) {
            int n = n0 + wn + fg * 4 + reg;
            O[((size_t)(tb * 512 + n) << 9) + c] = acc_o[j][reg];
        }
    }
}

// ---------------------------------------------------------------------------
__global__ void lif_ret(float* __restrict__ OR, int* __restrict__ ctr,
                        int* __restrict__ list) {
    int g = blockIdx.x * TPB + threadIdx.x;
    int c = g & 511, n = (g >> 9) & 511, b = g >> 18;
    double v = 0.0, eb = 0.0;
    bool flag = false;
    for (int t = 0; t < 4; ++t) {
        size_t idx = ((size_t)((t * 8 + b) * 512 + n) << 9) + c;
        double x = (double)OR[idx];
        double hh = v + (x - v) * 0.5;
        eb = 0.5 * eb + 0.5 * (fabs(x) * 1e-4);
        flag |= fabs(hh - 0.5) <= eb + 1e-9;
        bool s = hh >= 0.5;
        OR[idx] = s ? 1.0f : 0.0f;
        v = s ? 0.0 : hh;
        if (s) eb = 0.0;
    }
    if (flag) {
        int i2 = atomicAdd(ctr + 4, 1);
        if (i2 < FCAP) list[i2] = g;
    }
}

__global__ void repair_ret(const u64* __restrict__ qm, const u64* __restrict__ km,
                           const u64* __restrict__ vm, const double* __restrict__ pw,
                           const int* __restrict__ ctr, const int* __restrict__ list,
                           float* __restrict__ r) {
    int cnt = ctr[4]; if (cnt > FCAP) cnt = FCAP;
    int wv = (blockIdx.x * blockDim.x + threadIdx.x) >> 6;
    int nw = (gridDim.x * blockDim.x) >> 6;
    int lane = threadIdx.x & 63;
    for (int i = wv; i < cnt; i += nw) {
        int g = list[i];
        int c = g & 511, n = (g >> 9) & 511, b = g >> 18;
        int h = c >> 6, d = c & 63;
        double acc_t[4];
        for (int t = 0; t < 4; ++t) {
            int base = ((t * 8 + b) * 8 + h) * 512;
            u64 qw = qm[base + n];
            double p = 0.0;
            for (int j = 0; j < 8; ++j) {
                int m = j * 64 + lane;
                u64 kk = km[base + m];
                u64 vv = vm[base + m];
                if ((vv >> d) & 1ull) {
                    int dist = n - m; if (dist < 0) dist = -dist;
                    p += (double)__popcll(qw & kk) * pw[h * 512 + dist];
                }
            }
            acc_t[t] = p;
        }
        #pragma unroll
        for (int off = 32; off; off >>= 1) {
            #pragma unroll
            for (int t = 0; t < 4; ++t) acc_t[t] += __shfl_xor(acc_t[t], off, 64);
        }
        if (lane == 0) {
            double v = 0.0;
            for (int t = 0; t < 4; ++t) {
                double x = acc_t[t] * 0.125;
                double hh = v + (x - v) * 0.5;
                bool s = hh >= 0.5;
                r[((size_t)((t * 8 + b) * 512 + n) << 9) + c] = s ? 1.0f : 0.0f;
                v = s ? 0.0 : hh;
            }
        }
    }
}

// ---------------------------------------------------------------------------
__global__ void final_flag(const float* __restrict__ Y, int* __restrict__ ctr,
                           int* __restrict__ list) {
    int g = blockIdx.x * TPB + threadIdx.x;
    int c = g & 511, n = (g >> 9) & 511, b = g >> 18;
    double v = 0.0;
    bool flag = false;
    for (int t = 0; t < 4; ++t) {
        float y = Y[((size_t)((t * 8 + b) * 512 + n) << 9) + c];
        double hh = v + ((double)y - v) * 0.5;
        flag |= fabs(hh - 1.0) < MARGIN;
        bool s = hh >= 1.0;
        v = s ? 0.0 : hh;
    }
    if (flag) {
        int idx = atomicAdd(ctr + 3, 1);
        if (idx < FCAP) list[idx] = g;
    }
}

__global__ void fix_final(const float* __restrict__ rr, const float* __restrict__ w,
                          const float* __restrict__ bias,
                          const float* __restrict__ bnw, const float* __restrict__ bnb,
                          const float* __restrict__ bnm, const float* __restrict__ bnv,
                          const int* __restrict__ ctr, int* __restrict__ list) {
    int cnt = ctr[3]; if (cnt > FCAP) cnt = FCAP;
    int wv = (blockIdx.x * blockDim.x + threadIdx.x) >> 6;
    int nw = (gridDim.x * blockDim.x) >> 6;
    int lane = threadIdx.x & 63;
    for (int i = wv; i < cnt; i += nw) {
        int g = list[i] & 0x00FFFFFF;
        int c = g & 511, n = (g >> 9) & 511, b = g >> 18;
        const float* wr = w + (size_t)c * 512;
        double dot[4];
        #pragma unroll
        for (int t = 0; t < 4; ++t) {
            const float* xr = rr + ((size_t)((t * 8 + b) * 512 + n) << 9);
            double p = 0.0;
            #pragma unroll
            for (int j = 0; j < 8; ++j)
                p += (double)xr[lane + 64 * j] * (double)wr[lane + 64 * j];
            dot[t] = p;
        }
        #pragma unroll
        for (int off = 32; off; off >>= 1) {
            #pragma unroll
            for (int t = 0; t < 4; ++t)
                dot[t] += __shfl_xor(dot[t], off, 64);
        }
        if (lane == 0) {
            double inv = (double)bnw[c] / sqrt((double)bnv[c] + 1e-5);
            double sh  = (double)bnb[c] - (double)bnm[c] * inv;
            double bs  = (double)bias[c];
            double v = 0.0;
            int sp = 0;
            for (int t = 0; t < 4; ++t) {
                double y = (dot[t] + bs) * inv + sh;
                double hh = v + (y - v) * 0.5;
                bool s = hh >= 1.0;
                sp |= (s ? 1 : 0) << t;
                v = s ? 0.0 : hh;
            }
            list[i] = g | (sp << 24);
        }
    }
}

__global__ void final_write(const float* __restrict__ Y, float* __restrict__ out) {
    int g = blockIdx.x * TPB + threadIdx.x;
    int c = g & 511, n = (g >> 9) & 511, b = g >> 18;
    double v = 0.0;
    for (int t = 0; t < 4; ++t) {
        size_t idx = ((size_t)((t * 8 + b) * 512 + n) << 9) + c;
        float y = Y[idx];
        double hh = v + ((double)y - v) * 0.5;
        bool s = hh >= 1.0;
        out[idx] = s ? 1.0f : 0.0f;
        v = s ? 0.0 : hh;
    }
}

__global__ void fix_scatter(const int* __restrict__ ctr, const int* __restrict__ list,
                            float* __restrict__ out) {
    int cnt = ctr[3]; if (cnt > FCAP) cnt = FCAP;
    int i = blockIdx.x * blockDim.x + threadIdx.x;
    if (i >= cnt) return;
    int e = list[i];
    int g = e & 0x00FFFFFF, sp = (e >> 24) & 0xF;
    int c = g & 511, n = (g >> 9) & 511, b = g >> 18;
    for (int t = 0; t < 4; ++t)
        out[((size_t)((t * 8 + b) * 512 + n) << 9) + c] = ((sp >> t) & 1) ? 1.0f : 0.0f;
}

// ---------------------------------------------------------------------------
extern "C" void kernel_launch(void* const* d_in, const int* in_sizes, int n_in,
                              void* d_out, int out_size, void* d_ws, size_t ws_size,
                              hipStream_t stream) {
    const float* x = (const float*)d_in[0];
    const float *w[4], *bi[4], *bnw[4], *bnb[4], *bnm[4], *bnv[4];
    for (int br = 0; br < 4; ++br) {
        int base = 1 + br * 6;
        w[br]   = (const float*)d_in[base + 0];
        bi[br]  = (const float*)d_in[base + 1];
        bnw[br] = (const float*)d_in[base + 2];
        bnb[br] = (const float*)d_in[base + 3];
        bnm[br] = (const float*)d_in[base + 4];
        bnv[br] = (const float*)d_in[base + 5];
    }

    const size_t NX = (size_t)16384 * 512;   // 8.4M elements
    char* p = (char*)d_ws;
    double* pw = (double*)p;  p += 8 * 512 * sizeof(double);
    u64* qm = (u64*)p;        p += 131072 * sizeof(u64);
    u64* km = (u64*)p;        p += 131072 * sizeof(u64);
    u64* vm = (u64*)p;        p += 131072 * sizeof(u64);
    int* ctr = (int*)p;       p += 1024;
    int* list = (int*)p;      p += (size_t)FCAP * sizeof(int);
    float* Y = (float*)p;     p += NX * 4;                      // ~40.6 MB so far
    __bf16* Xh = (__bf16*)p;  p += NX * 2;                      // 16.8 MB
    __bf16* Xl = (__bf16*)p;  p += NX * 2;                      // 16.8 MB
    __bf16* Wsp = (__bf16*)p; p += (size_t)4 * 2 * 262144 * 2;  // 4 MB
    size_t need_fast = (size_t)(p - (char*)d_ws);
    int fast = ws_size >= need_fast;
    float* r = (float*)d_out;

    zero_counters<<<1, 64, 0, stream>>>(ctr);
    pow_kernel<<<1, 64, 0, stream>>>(pw);

    if (fast) {
        split_f32<<<8192, 256, 0, stream>>>(x, Xh, Xl, (int)NX);
        for (int br = 0; br < 4; ++br)
            split_f32<<<256, 256, 0, stream>>>(w[br], Wsp + (size_t)br * 524288,
                                               Wsp + (size_t)br * 524288 + 262144, 262144);
    }

    dim3 g2(128, 4);   // fast gemm grid (128x128 tiles)
    dim3 gg(128, 8);   // fallback gemm grid (128x64 tiles)

    for (int br = 0; br < 3; ++br) {
        u64* msk = br == 0 ? qm : (br == 1 ? km : vm);
        if (fast)
            gemm_bn_mfma2<<<g2, 256, 0, stream>>>(Xh, Xl,
                Wsp + (size_t)br * 524288, Wsp + (size_t)br * 524288 + 262144,
                bi[br], bnw[br], bnb[br], bnm[br], bnv[br], Y, 1);
        else
            gemm_bn_mfma<<<gg, 256, 0, stream>>>(x, w[br], bi[br], bnw[br], bnb[br],
                                                 bnm[br], bnv[br], Y);
        lif_mask_flag<<<8192, TPB, 0, stream>>>(Y, msk, ctr, list, br);
        fix_mask<<<128, 256, 0, stream>>>(x, w[br], bi[br], bnw[br], bnb[br],
                                          bnm[br], bnv[br], msk, ctr, list, br);
    }

    // fused retention -> O in d_out -> LIF in place -> exact repair
    ret_fused<<<2048, 256, 0, stream>>>(qm, km, vm, pw, (float*)d_out);
    lif_ret<<<8192, TPB, 0, stream>>>((float*)d_out, ctr, list);
    repair_ret<<<256, 256, 0, stream>>>(qm, km, vm, pw, ctr, list, (float*)d_out);

    // p projection: r is binary -> exact bf16 A, 2-pass gemm
    if (fast) {
        split_bin<<<8192, 256, 0, stream>>>(r, Xh, (int)NX);
        gemm_bn_mfma2<<<g2, 256, 0, stream>>>(Xh, Xh,
            Wsp + (size_t)3 * 524288, Wsp + (size_t)3 * 524288 + 262144,
            bi[3], bnw[3], bnb[3], bnm[3], bnv[3], Y, 0);
    } else {
        gemm_bn_mfma<<<gg, 256, 0, stream>>>(r, w[3], bi[3], bnw[3], bnb[3],
                                             bnm[3], bnv[3], Y);
    }
    final_flag<<<8192, TPB, 0, stream>>>(Y, ctr, list);
    fix_final<<<128, 256, 0, stream>>>(r, w[3], bi[3], bnw[3], bnb[3], bnm[3], bnv[3], ctr, list);
    final_write<<<8192, TPB, 0, stream>>>(Y, (float*)d_out);
    fix_scatter<<<4096, 256, 0, stream>>>(ctr, list, (float*)d_out);
}